// Round 4
// baseline (331.323 us; speedup 1.0000x reference)
//
#include <hip/hip_runtime.h>

#define N_NODES 100000
#define N_EDGES 1600000
#define D_IN 32
#define D_HID 16
#define D_OUT 2

// Node bucketing: 128 nodes/bucket -> LDS tile 128x16 f32 (stride-17 padded).
#define NPB 128
#define NB 782                    // ceil(100000/128)
#define BIN_CHUNK 8192
#define BIN_BLOCKS ((N_EDGES + BIN_CHUNK - 1) / BIN_CHUNK)   // 196
#define HIST_CHUNK 4096
#define HIST_BLOCKS ((N_EDGES + HIST_CHUNK - 1) / HIST_CHUNK) // 391
#define ACC_TILE 512              // records staged in LDS per tile

// ---------------------------------------------------------------------------
// Kernel 1: per-node dense transforms for layer 1 (+ zero bucket histogram).
//   xr[i]  = x[i] @ w1_rel^T
//   agg[i] = x[i] @ w1_root^T + b1
// ---------------------------------------------------------------------------
__global__ __launch_bounds__(256) void k_node1(
    const float* __restrict__ x,
    const float* __restrict__ w_rel, const float* __restrict__ w_root,
    const float* __restrict__ b,
    float* __restrict__ xr, float* __restrict__ agg,
    int* __restrict__ gdeg)
{
    __shared__ float s_rel[D_HID * D_IN];
    __shared__ float s_root[D_HID * D_IN];
    __shared__ float s_b[D_HID];
    for (int i = threadIdx.x; i < D_HID * D_IN; i += blockDim.x) {
        s_rel[i]  = w_rel[i];
        s_root[i] = w_root[i];
    }
    if (threadIdx.x < D_HID) s_b[threadIdx.x] = b[threadIdx.x];
    if (blockIdx.x == 0)
        for (int i = threadIdx.x; i < NB; i += blockDim.x) gdeg[i] = 0;
    __syncthreads();

    int node = blockIdx.x * blockDim.x + threadIdx.x;
    if (node >= N_NODES) return;

    float row[D_IN];
    const float4* xp = (const float4*)(x + (size_t)node * D_IN);
#pragma unroll
    for (int i = 0; i < D_IN / 4; i++) {
        float4 v = xp[i];
        row[4*i+0] = v.x; row[4*i+1] = v.y; row[4*i+2] = v.z; row[4*i+3] = v.w;
    }

    float oa[D_HID], orr[D_HID];
#pragma unroll
    for (int o = 0; o < D_HID; o++) {
        float a = 0.f, r = s_b[o];
#pragma unroll
        for (int k = 0; k < D_IN; k++) {
            a += row[k] * s_rel[o * D_IN + k];
            r += row[k] * s_root[o * D_IN + k];
        }
        oa[o] = a; orr[o] = r;
    }

    float4* xrp  = (float4*)(xr  + (size_t)node * D_HID);
    float4* aggp = (float4*)(agg + (size_t)node * D_HID);
#pragma unroll
    for (int i = 0; i < D_HID / 4; i++) {
        xrp[i]  = make_float4(oa[4*i], oa[4*i+1], oa[4*i+2], oa[4*i+3]);
        aggp[i] = make_float4(orr[4*i], orr[4*i+1], orr[4*i+2], orr[4*i+3]);
    }
}

// ---------------------------------------------------------------------------
// Bucket histogram: LDS-reduced per block, then NB global adds per block.
// ---------------------------------------------------------------------------
__global__ __launch_bounds__(512) void k_histb(
    const int* __restrict__ ei, int* __restrict__ gdeg)
{
    __shared__ int h[NB];
    for (int i = threadIdx.x; i < NB; i += 512) h[i] = 0;
    __syncthreads();
    int e0 = blockIdx.x * HIST_CHUNK;
    int e1 = min(e0 + HIST_CHUNK, N_EDGES);
    for (int e = e0 + threadIdx.x; e < e1; e += 512)
        atomicAdd(&h[ei[N_EDGES + e] >> 7], 1);
    __syncthreads();
    for (int i = threadIdx.x; i < NB; i += 512)
        if (h[i]) atomicAdd(&gdeg[i], h[i]);
}

// ---------------------------------------------------------------------------
// Exclusive scan of the NB bucket counts (single block).
// ---------------------------------------------------------------------------
__global__ __launch_bounds__(1024) void k_scan(
    const int* __restrict__ gdeg, int* __restrict__ base, int* __restrict__ cursor)
{
    __shared__ int s[1024];
    int v = (threadIdx.x < NB) ? gdeg[threadIdx.x] : 0;
    s[threadIdx.x] = v;
    __syncthreads();
#pragma unroll
    for (int off = 1; off < 1024; off <<= 1) {
        int t = (threadIdx.x >= off) ? s[threadIdx.x - off] : 0;
        __syncthreads();
        s[threadIdx.x] += t;
        __syncthreads();
    }
    if (threadIdx.x < NB) {
        int ex = s[threadIdx.x] - v;
        base[threadIdx.x] = ex;
        cursor[threadIdx.x] = ex;
    }
    if (threadIdx.x == 0) base[NB] = N_EDGES;
}

// ---------------------------------------------------------------------------
// Bin edges into bucket-ordered record array. Per-block cursor reservation
// makes the writes sequential within each bucket (no line thrashing).
// Record: (dst&127) << 17 | src   (src < 2^17).
// ---------------------------------------------------------------------------
__global__ __launch_bounds__(512) void k_bin(
    const int* __restrict__ ei, int* __restrict__ cursor,
    unsigned int* __restrict__ recs)
{
    __shared__ int cnt[NB];
    __shared__ int loc[NB];
    __shared__ int cur[NB];
    for (int i = threadIdx.x; i < NB; i += 512) { cnt[i] = 0; cur[i] = 0; }
    __syncthreads();
    int e0 = blockIdx.x * BIN_CHUNK;
    int e1 = min(e0 + BIN_CHUNK, N_EDGES);
    for (int e = e0 + threadIdx.x; e < e1; e += 512)
        atomicAdd(&cnt[ei[N_EDGES + e] >> 7], 1);
    __syncthreads();
    for (int i = threadIdx.x; i < NB; i += 512)
        if (cnt[i] > 0) loc[i] = atomicAdd(&cursor[i], cnt[i]);
    __syncthreads();
    for (int e = e0 + threadIdx.x; e < e1; e += 512) {
        int src = ei[e];
        int dst = ei[N_EDGES + e];
        int bkt = dst >> 7;
        int idx = atomicAdd(&cur[bkt], 1);
        recs[loc[bkt] + idx] = ((unsigned)(dst & (NPB - 1)) << 17) | (unsigned)src;
    }
}

// ---------------------------------------------------------------------------
// Layer-1 accumulate v2: one block per bucket.
//  - Records staged in LDS tiles (coalesced) -> recs off the dependent chain.
//  - 16 lanes per record gather one 64B line of xr; 4x manual unroll -> 16
//    independent line-gathers in flight per wave (MLP, not latency chain).
//  - ds_add into padded 128x16 tile, then one sequential agg += write.
// ---------------------------------------------------------------------------
__global__ __launch_bounds__(512) void k_acc1(
    const int* __restrict__ base, const unsigned int* __restrict__ recs,
    const float* __restrict__ xr, float* __restrict__ agg)
{
    __shared__ float s[NPB * 17];          // 8704 B
    __shared__ unsigned rbuf[ACC_TILE];    // 2048 B
    for (int i = threadIdx.x; i < NPB * 17; i += 512) s[i] = 0.f;
    __syncthreads();

    int b = blockIdx.x;
    int r0 = base[b], r1 = base[b + 1];
    int f = threadIdx.x & (D_HID - 1);
    int g = threadIdx.x >> 4;              // 0..31 record-group within block

    for (int t = r0; t < r1; t += ACC_TILE) {
        int n = min(ACC_TILE, r1 - t);
        if (threadIdx.x < n) rbuf[threadIdx.x] = recs[t + threadIdx.x];
        __syncthreads();
        int i = g;
        for (; i + 96 < n; i += 128) {
            unsigned c0 = rbuf[i];
            unsigned c1 = rbuf[i + 32];
            unsigned c2 = rbuf[i + 64];
            unsigned c3 = rbuf[i + 96];
            float v0 = xr[(c0 & 0x1FFFF) * D_HID + f];
            float v1 = xr[(c1 & 0x1FFFF) * D_HID + f];
            float v2 = xr[(c2 & 0x1FFFF) * D_HID + f];
            float v3 = xr[(c3 & 0x1FFFF) * D_HID + f];
            atomicAdd(&s[(c0 >> 17) * 17 + f], v0);
            atomicAdd(&s[(c1 >> 17) * 17 + f], v1);
            atomicAdd(&s[(c2 >> 17) * 17 + f], v2);
            atomicAdd(&s[(c3 >> 17) * 17 + f], v3);
        }
        for (; i < n; i += 32) {
            unsigned c = rbuf[i];
            atomicAdd(&s[(c >> 17) * 17 + f], xr[(c & 0x1FFFF) * D_HID + f]);
        }
        __syncthreads();
    }

    int nodebase = b * NPB;
    for (int t = threadIdx.x; t < NPB * D_HID; t += 512) {
        int dl = t >> 4, ff = t & (D_HID - 1);
        int node = nodebase + dl;
        if (node < N_NODES) agg[node * D_HID + ff] += s[dl * 17 + ff];
    }
}

// ---------------------------------------------------------------------------
// relu + per-node dense transforms for layer 2.
// ---------------------------------------------------------------------------
__global__ __launch_bounds__(256) void k_node2(
    const float* __restrict__ agg,
    const float* __restrict__ w_rel, const float* __restrict__ w_root,
    const float* __restrict__ b,
    float* __restrict__ hr, float* __restrict__ outv)
{
    __shared__ float s_rel[D_OUT * D_HID];
    __shared__ float s_root[D_OUT * D_HID];
    __shared__ float s_b[D_OUT];
    for (int i = threadIdx.x; i < D_OUT * D_HID; i += blockDim.x) {
        s_rel[i]  = w_rel[i];
        s_root[i] = w_root[i];
    }
    if (threadIdx.x < D_OUT) s_b[threadIdx.x] = b[threadIdx.x];
    __syncthreads();

    int node = blockIdx.x * blockDim.x + threadIdx.x;
    if (node >= N_NODES) return;

    float h[D_HID];
    const float4* ap = (const float4*)(agg + (size_t)node * D_HID);
#pragma unroll
    for (int i = 0; i < D_HID / 4; i++) {
        float4 v = ap[i];
        h[4*i+0] = fmaxf(v.x, 0.f); h[4*i+1] = fmaxf(v.y, 0.f);
        h[4*i+2] = fmaxf(v.z, 0.f); h[4*i+3] = fmaxf(v.w, 0.f);
    }

    float o_rel[D_OUT], o_root[D_OUT];
#pragma unroll
    for (int o = 0; o < D_OUT; o++) {
        float a = 0.f, r = s_b[o];
#pragma unroll
        for (int k = 0; k < D_HID; k++) {
            a += h[k] * s_rel[o * D_HID + k];
            r += h[k] * s_root[o * D_HID + k];
        }
        o_rel[o] = a; o_root[o] = r;
    }

    ((float2*)(hr   + (size_t)node * D_OUT))[0] = make_float2(o_rel[0], o_rel[1]);
    ((float2*)(outv + (size_t)node * D_OUT))[0] = make_float2(o_root[0], o_root[1]);
}

// ---------------------------------------------------------------------------
// Layer-2 accumulate v2: records staged in LDS; one record per thread per
// tile -> each wave's float2 gather of hr puts up to 64 lines in flight.
// hr is 0.8 MB (L2-resident). LDS tile 128x2 via ds_add, sequential out +=.
// ---------------------------------------------------------------------------
__global__ __launch_bounds__(512) void k_acc2(
    const int* __restrict__ base, const unsigned int* __restrict__ recs,
    const float* __restrict__ hr, float* __restrict__ outv)
{
    __shared__ float s[NPB * D_OUT];       // 1 KB
    __shared__ unsigned rbuf[ACC_TILE];
    for (int i = threadIdx.x; i < NPB * D_OUT; i += 512) s[i] = 0.f;
    __syncthreads();

    int b = blockIdx.x;
    int r0 = base[b], r1 = base[b + 1];

    for (int t = r0; t < r1; t += ACC_TILE) {
        int n = min(ACC_TILE, r1 - t);
        if (threadIdx.x < n) rbuf[threadIdx.x] = recs[t + threadIdx.x];
        __syncthreads();
        if (threadIdx.x < n) {
            unsigned c = rbuf[threadIdx.x];
            int src = c & 0x1FFFF;
            int dl  = c >> 17;
            float2 v = *(const float2*)(hr + (size_t)src * D_OUT);
            atomicAdd(&s[dl * D_OUT + 0], v.x);
            atomicAdd(&s[dl * D_OUT + 1], v.y);
        }
        __syncthreads();
    }

    int nodebase = b * NPB;
    for (int t = threadIdx.x; t < NPB * D_OUT; t += 512) {
        int node = nodebase + (t >> 1);
        if (node < N_NODES) outv[node * D_OUT + (t & 1)] += s[t];
    }
}

extern "C" void kernel_launch(void* const* d_in, const int* in_sizes, int n_in,
                              void* d_out, int out_size, void* d_ws, size_t ws_size,
                              hipStream_t stream) {
    const float* x       = (const float*)d_in[0];
    const int*   ei      = (const int*)  d_in[1];
    const float* w1_rel  = (const float*)d_in[2];
    const float* w1_root = (const float*)d_in[3];
    const float* b1      = (const float*)d_in[4];
    const float* w2_rel  = (const float*)d_in[5];
    const float* w2_root = (const float*)d_in[6];
    const float* b2      = (const float*)d_in[7];
    float* out = (float*)d_out;

    // Workspace layout (~20.1 MB, all rewritten each call):
    float*        xr     = (float*)d_ws;                          // N*D_HID
    float*        agg    = xr  + (size_t)N_NODES * D_HID;         // N*D_HID
    float*        hr     = agg + (size_t)N_NODES * D_HID;         // N*D_OUT
    unsigned int* recs   = (unsigned int*)(hr + (size_t)N_NODES * D_OUT); // E
    int*          gdeg   = (int*)(recs + N_EDGES);                // NB
    int*          base   = gdeg + NB;                             // NB+1
    int*          cursor = base + NB + 1;                         // NB

    k_node1<<<dim3((N_NODES + 255) / 256), dim3(256), 0, stream>>>(
        x, w1_rel, w1_root, b1, xr, agg, gdeg);

    k_histb<<<dim3(HIST_BLOCKS), dim3(512), 0, stream>>>(ei, gdeg);

    k_scan<<<dim3(1), dim3(1024), 0, stream>>>(gdeg, base, cursor);

    k_bin<<<dim3(BIN_BLOCKS), dim3(512), 0, stream>>>(ei, cursor, recs);

    k_acc1<<<dim3(NB), dim3(512), 0, stream>>>(base, recs, xr, agg);

    k_node2<<<dim3((N_NODES + 255) / 256), dim3(256), 0, stream>>>(
        agg, w2_rel, w2_root, b2, hr, out);

    k_acc2<<<dim3(NB), dim3(512), 0, stream>>>(base, recs, hr, out);
}

// Round 5
// 269.208 us; speedup vs baseline: 1.2307x; 1.2307x over previous
//
#include <hip/hip_runtime.h>

#define N_NODES 100000
#define N_EDGES 1600000
#define D_IN 32
#define D_HID 16
#define D_OUT 2

// Node bucketing for dst-locality of the atomic destinations.
#define NPB 128
#define NB 782                    // ceil(100000/128)
#define BIN_CHUNK 8192
#define BIN_BLOCKS ((N_EDGES + BIN_CHUNK - 1) / BIN_CHUNK)   // 196
#define HIST_CHUNK 4096
#define HIST_BLOCKS ((N_EDGES + HIST_CHUNK - 1) / HIST_CHUNK) // 391

#define A1_RPT 4                      // records per thread-group in k_acc1
#define A1_RPB (16 * A1_RPT)          // 64 records per 256-thread block
#define A1_BLOCKS (N_EDGES / A1_RPB)  // 25000 (exact)

#define A2_RPB 256                    // records per 256-thread block in k_acc2
#define A2_BLOCKS (8 * 782)           // 6256, covers 1,601,536 slots w/ guard

// ---------------------------------------------------------------------------
// Kernel 1: per-node dense transforms for layer 1 (+ zero bucket histogram).
//   xr[i]  = x[i] @ w1_rel^T
//   agg[i] = x[i] @ w1_root^T + b1
// ---------------------------------------------------------------------------
__global__ __launch_bounds__(256) void k_node1(
    const float* __restrict__ x,
    const float* __restrict__ w_rel, const float* __restrict__ w_root,
    const float* __restrict__ b,
    float* __restrict__ xr, float* __restrict__ agg,
    int* __restrict__ gdeg)
{
    __shared__ float s_rel[D_HID * D_IN];
    __shared__ float s_root[D_HID * D_IN];
    __shared__ float s_b[D_HID];
    for (int i = threadIdx.x; i < D_HID * D_IN; i += blockDim.x) {
        s_rel[i]  = w_rel[i];
        s_root[i] = w_root[i];
    }
    if (threadIdx.x < D_HID) s_b[threadIdx.x] = b[threadIdx.x];
    if (blockIdx.x == 0)
        for (int i = threadIdx.x; i < NB; i += blockDim.x) gdeg[i] = 0;
    __syncthreads();

    int node = blockIdx.x * blockDim.x + threadIdx.x;
    if (node >= N_NODES) return;

    float row[D_IN];
    const float4* xp = (const float4*)(x + (size_t)node * D_IN);
#pragma unroll
    for (int i = 0; i < D_IN / 4; i++) {
        float4 v = xp[i];
        row[4*i+0] = v.x; row[4*i+1] = v.y; row[4*i+2] = v.z; row[4*i+3] = v.w;
    }

    float oa[D_HID], orr[D_HID];
#pragma unroll
    for (int o = 0; o < D_HID; o++) {
        float a = 0.f, r = s_b[o];
#pragma unroll
        for (int k = 0; k < D_IN; k++) {
            a += row[k] * s_rel[o * D_IN + k];
            r += row[k] * s_root[o * D_IN + k];
        }
        oa[o] = a; orr[o] = r;
    }

    float4* xrp  = (float4*)(xr  + (size_t)node * D_HID);
    float4* aggp = (float4*)(agg + (size_t)node * D_HID);
#pragma unroll
    for (int i = 0; i < D_HID / 4; i++) {
        xrp[i]  = make_float4(oa[4*i], oa[4*i+1], oa[4*i+2], oa[4*i+3]);
        aggp[i] = make_float4(orr[4*i], orr[4*i+1], orr[4*i+2], orr[4*i+3]);
    }
}

// ---------------------------------------------------------------------------
// Bucket histogram: LDS-reduced per block, then NB global adds per block.
// ---------------------------------------------------------------------------
__global__ __launch_bounds__(512) void k_histb(
    const int* __restrict__ ei, int* __restrict__ gdeg)
{
    __shared__ int h[NB];
    for (int i = threadIdx.x; i < NB; i += 512) h[i] = 0;
    __syncthreads();
    int e0 = blockIdx.x * HIST_CHUNK;
    int e1 = min(e0 + HIST_CHUNK, N_EDGES);
    for (int e = e0 + threadIdx.x; e < e1; e += 512)
        atomicAdd(&h[ei[N_EDGES + e] >> 7], 1);
    __syncthreads();
    for (int i = threadIdx.x; i < NB; i += 512)
        if (h[i]) atomicAdd(&gdeg[i], h[i]);
}

// ---------------------------------------------------------------------------
// Exclusive scan of the NB bucket counts (single block).
// ---------------------------------------------------------------------------
__global__ __launch_bounds__(1024) void k_scan(
    const int* __restrict__ gdeg, int* __restrict__ base, int* __restrict__ cursor)
{
    __shared__ int s[1024];
    int v = (threadIdx.x < NB) ? gdeg[threadIdx.x] : 0;
    s[threadIdx.x] = v;
    __syncthreads();
#pragma unroll
    for (int off = 1; off < 1024; off <<= 1) {
        int t = (threadIdx.x >= off) ? s[threadIdx.x - off] : 0;
        __syncthreads();
        s[threadIdx.x] += t;
        __syncthreads();
    }
    if (threadIdx.x < NB) {
        int ex = s[threadIdx.x] - v;
        base[threadIdx.x] = ex;
        cursor[threadIdx.x] = ex;
    }
    if (threadIdx.x == 0) base[NB] = N_EDGES;
}

// ---------------------------------------------------------------------------
// Bin edges into bucket-ordered record array recs[r] = {src, dst}.
// Per-block cursor reservation keeps writes near-sequential per bucket.
// ---------------------------------------------------------------------------
__global__ __launch_bounds__(512) void k_bin(
    const int* __restrict__ ei, int* __restrict__ cursor,
    uint2* __restrict__ recs)
{
    __shared__ int cnt[NB];
    __shared__ int loc[NB];
    __shared__ int cur[NB];
    for (int i = threadIdx.x; i < NB; i += 512) { cnt[i] = 0; cur[i] = 0; }
    __syncthreads();
    int e0 = blockIdx.x * BIN_CHUNK;
    int e1 = min(e0 + BIN_CHUNK, N_EDGES);
    for (int e = e0 + threadIdx.x; e < e1; e += 512)
        atomicAdd(&cnt[ei[N_EDGES + e] >> 7], 1);
    __syncthreads();
    for (int i = threadIdx.x; i < NB; i += 512)
        if (cnt[i] > 0) loc[i] = atomicAdd(&cursor[i], cnt[i]);
    __syncthreads();
    for (int e = e0 + threadIdx.x; e < e1; e += 512) {
        int src = ei[e];
        int dst = ei[N_EDGES + e];
        int bkt = dst >> 7;
        int idx = atomicAdd(&cur[bkt], 1);
        recs[loc[bkt] + idx] = make_uint2((unsigned)src, (unsigned)dst);
    }
}

// ---------------------------------------------------------------------------
// Layer-1 accumulate v3: massively-parallel fire-and-forget atomics.
// 16 lanes per record gather one 64B line of xr; 4 independent records per
// thread-group -> 16 lines in flight per wave; atomics are no-return (no
// stall) and dst-window-local thanks to binning (stay hot in L2).
// XCD-swizzle: consecutive record chunks stay on one XCD.
// ---------------------------------------------------------------------------
__global__ __launch_bounds__(256) void k_acc1(
    const uint2* __restrict__ recs,
    const float* __restrict__ xr, float* __restrict__ agg)
{
    int p = blockIdx.x;
    int c = (p & 7) * (A1_BLOCKS / 8) + (p >> 3);   // XCD-contiguous chunks
    int g = threadIdx.x >> 4;
    int f = threadIdx.x & (D_HID - 1);
    int r0 = c * A1_RPB + g;
    uint2 e0 = recs[r0];
    uint2 e1 = recs[r0 + 16];
    uint2 e2 = recs[r0 + 32];
    uint2 e3 = recs[r0 + 48];
    float v0 = xr[e0.x * D_HID + f];
    float v1 = xr[e1.x * D_HID + f];
    float v2 = xr[e2.x * D_HID + f];
    float v3 = xr[e3.x * D_HID + f];
    atomicAdd(&agg[e0.y * D_HID + f], v0);
    atomicAdd(&agg[e1.y * D_HID + f], v1);
    atomicAdd(&agg[e2.y * D_HID + f], v2);
    atomicAdd(&agg[e3.y * D_HID + f], v3);
}

// ---------------------------------------------------------------------------
// relu + per-node dense transforms for layer 2.
// ---------------------------------------------------------------------------
__global__ __launch_bounds__(256) void k_node2(
    const float* __restrict__ agg,
    const float* __restrict__ w_rel, const float* __restrict__ w_root,
    const float* __restrict__ b,
    float* __restrict__ hr, float* __restrict__ outv)
{
    __shared__ float s_rel[D_OUT * D_HID];
    __shared__ float s_root[D_OUT * D_HID];
    __shared__ float s_b[D_OUT];
    for (int i = threadIdx.x; i < D_OUT * D_HID; i += blockDim.x) {
        s_rel[i]  = w_rel[i];
        s_root[i] = w_root[i];
    }
    if (threadIdx.x < D_OUT) s_b[threadIdx.x] = b[threadIdx.x];
    __syncthreads();

    int node = blockIdx.x * blockDim.x + threadIdx.x;
    if (node >= N_NODES) return;

    float h[D_HID];
    const float4* ap = (const float4*)(agg + (size_t)node * D_HID);
#pragma unroll
    for (int i = 0; i < D_HID / 4; i++) {
        float4 v = ap[i];
        h[4*i+0] = fmaxf(v.x, 0.f); h[4*i+1] = fmaxf(v.y, 0.f);
        h[4*i+2] = fmaxf(v.z, 0.f); h[4*i+3] = fmaxf(v.w, 0.f);
    }

    float o_rel[D_OUT], o_root[D_OUT];
#pragma unroll
    for (int o = 0; o < D_OUT; o++) {
        float a = 0.f, r = s_b[o];
#pragma unroll
        for (int k = 0; k < D_HID; k++) {
            a += h[k] * s_rel[o * D_HID + k];
            r += h[k] * s_root[o * D_HID + k];
        }
        o_rel[o] = a; o_root[o] = r;
    }

    ((float2*)(hr   + (size_t)node * D_OUT))[0] = make_float2(o_rel[0], o_rel[1]);
    ((float2*)(outv + (size_t)node * D_OUT))[0] = make_float2(o_root[0], o_root[1]);
}

// ---------------------------------------------------------------------------
// Layer-2 accumulate v3: 2 lanes per record, 2 records per thread, global
// fire-and-forget atomics into dst-window-local out lines. hr is 0.8 MB
// (L2-resident gathers).
// ---------------------------------------------------------------------------
__global__ __launch_bounds__(256) void k_acc2(
    const uint2* __restrict__ recs,
    const float* __restrict__ hr, float* __restrict__ outv)
{
    int p = blockIdx.x;
    int c = (p & 7) * 782 + (p >> 3);
    int g = threadIdx.x >> 1;
    int f = threadIdx.x & (D_OUT - 1);
    int r0 = c * A2_RPB + g;
    if (r0 < N_EDGES) {
        uint2 e = recs[r0];
        atomicAdd(&outv[e.y * D_OUT + f], hr[e.x * D_OUT + f]);
    }
    int r1 = r0 + 128;
    if (r1 < N_EDGES) {
        uint2 e = recs[r1];
        atomicAdd(&outv[e.y * D_OUT + f], hr[e.x * D_OUT + f]);
    }
}

extern "C" void kernel_launch(void* const* d_in, const int* in_sizes, int n_in,
                              void* d_out, int out_size, void* d_ws, size_t ws_size,
                              hipStream_t stream) {
    const float* x       = (const float*)d_in[0];
    const int*   ei      = (const int*)  d_in[1];
    const float* w1_rel  = (const float*)d_in[2];
    const float* w1_root = (const float*)d_in[3];
    const float* b1      = (const float*)d_in[4];
    const float* w2_rel  = (const float*)d_in[5];
    const float* w2_root = (const float*)d_in[6];
    const float* b2      = (const float*)d_in[7];
    float* out = (float*)d_out;

    // Workspace layout (~26.5 MB, all rewritten each call):
    float* xr   = (float*)d_ws;                                   // N*D_HID
    float* agg  = xr  + (size_t)N_NODES * D_HID;                  // N*D_HID
    float* hr   = agg + (size_t)N_NODES * D_HID;                  // N*D_OUT
    uint2* recs = (uint2*)(hr + (size_t)N_NODES * D_OUT);         // E uint2
    int*   gdeg = (int*)(recs + N_EDGES);                         // NB
    int*   base = gdeg + NB;                                      // NB+1
    int*   cursor = base + NB + 1;                                // NB

    k_node1<<<dim3((N_NODES + 255) / 256), dim3(256), 0, stream>>>(
        x, w1_rel, w1_root, b1, xr, agg, gdeg);

    k_histb<<<dim3(HIST_BLOCKS), dim3(512), 0, stream>>>(ei, gdeg);

    k_scan<<<dim3(1), dim3(1024), 0, stream>>>(gdeg, base, cursor);

    k_bin<<<dim3(BIN_BLOCKS), dim3(512), 0, stream>>>(ei, cursor, recs);

    k_acc1<<<dim3(A1_BLOCKS), dim3(256), 0, stream>>>(recs, xr, agg);

    k_node2<<<dim3((N_NODES + 255) / 256), dim3(256), 0, stream>>>(
        agg, w2_rel, w2_root, b2, hr, out);

    k_acc2<<<dim3(A2_BLOCKS), dim3(256), 0, stream>>>(recs, hr, out);
}

// Round 6
// 236.514 us; speedup vs baseline: 1.4009x; 1.1382x over previous
//
#include <hip/hip_runtime.h>

#define N_NODES 100000
#define N_EDGES 1600000
#define D_IN 32
#define D_HID 16
#define D_OUT 2

// dst bucketing: 128 nodes per bucket.
#define NPB 128
#define NB 782                                                // ceil(100000/128)
#define HIST_CHUNK 16384
#define HIST_BLOCKS ((N_EDGES + HIST_CHUNK - 1) / HIST_CHUNK) // 98
#define BIN_CHUNK 16384
#define BIN_BLOCKS ((N_EDGES + BIN_CHUNK - 1) / BIN_CHUNK)    // 98

// Accumulate kernel: each 16-lane group owns a contiguous chunk of ACC_K
// records; a wave covers 4*ACC_K records. 1.6M / 32 = 50000 waves exactly.
#define ACC_K 8
#define ACC_BLOCKS (N_EDGES / (4 * ACC_K) / 4)                // 12500

// ---------------------------------------------------------------------------
// Per-node dense transforms for layer 1.
//   xr[i]  = x[i] @ w1_rel^T     (gathered over edges later)
//   agg[i] = x[i] @ w1_root^T + b1   (atomic accumulator pre-init with root)
// ---------------------------------------------------------------------------
__global__ __launch_bounds__(256) void k_node1(
    const float* __restrict__ x,
    const float* __restrict__ w_rel, const float* __restrict__ w_root,
    const float* __restrict__ b,
    float* __restrict__ xr, float* __restrict__ agg)
{
    __shared__ float s_rel[D_HID * D_IN];
    __shared__ float s_root[D_HID * D_IN];
    __shared__ float s_b[D_HID];
    for (int i = threadIdx.x; i < D_HID * D_IN; i += blockDim.x) {
        s_rel[i]  = w_rel[i];
        s_root[i] = w_root[i];
    }
    if (threadIdx.x < D_HID) s_b[threadIdx.x] = b[threadIdx.x];
    __syncthreads();

    int node = blockIdx.x * blockDim.x + threadIdx.x;
    if (node >= N_NODES) return;

    float row[D_IN];
    const float4* xp = (const float4*)(x + (size_t)node * D_IN);
#pragma unroll
    for (int i = 0; i < D_IN / 4; i++) {
        float4 v = xp[i];
        row[4*i+0] = v.x; row[4*i+1] = v.y; row[4*i+2] = v.z; row[4*i+3] = v.w;
    }

    float oa[D_HID], orr[D_HID];
#pragma unroll
    for (int o = 0; o < D_HID; o++) {
        float a = 0.f, r = s_b[o];
#pragma unroll
        for (int k = 0; k < D_IN; k++) {
            a += row[k] * s_rel[o * D_IN + k];
            r += row[k] * s_root[o * D_IN + k];
        }
        oa[o] = a; orr[o] = r;
    }

    float4* xrp  = (float4*)(xr  + (size_t)node * D_HID);
    float4* aggp = (float4*)(agg + (size_t)node * D_HID);
#pragma unroll
    for (int i = 0; i < D_HID / 4; i++) {
        xrp[i]  = make_float4(oa[4*i], oa[4*i+1], oa[4*i+2], oa[4*i+3]);
        aggp[i] = make_float4(orr[4*i], orr[4*i+1], orr[4*i+2], orr[4*i+3]);
    }
}

// ---------------------------------------------------------------------------
// Bucket histogram: LDS-reduced per block, NB global adds per block.
// 98 blocks -> ~77k global int-atomic transactions.
// ---------------------------------------------------------------------------
__global__ __launch_bounds__(512) void k_histb(
    const int* __restrict__ ei, int* __restrict__ gdeg)
{
    __shared__ int h[NB];
    for (int i = threadIdx.x; i < NB; i += 512) h[i] = 0;
    __syncthreads();
    int e0 = blockIdx.x * HIST_CHUNK;
    int e1 = min(e0 + HIST_CHUNK, N_EDGES);
    for (int e = e0 + threadIdx.x; e < e1; e += 512)
        atomicAdd(&h[ei[N_EDGES + e] >> 7], 1);
    __syncthreads();
    for (int i = threadIdx.x; i < NB; i += 512)
        if (h[i]) atomicAdd(&gdeg[i], h[i]);
}

// ---------------------------------------------------------------------------
// Exclusive scan of the NB bucket counts (single block).
// ---------------------------------------------------------------------------
__global__ __launch_bounds__(1024) void k_scan(
    const int* __restrict__ gdeg, int* __restrict__ base, int* __restrict__ cursor)
{
    __shared__ int s[1024];
    int v = (threadIdx.x < NB) ? gdeg[threadIdx.x] : 0;
    s[threadIdx.x] = v;
    __syncthreads();
#pragma unroll
    for (int off = 1; off < 1024; off <<= 1) {
        int t = (threadIdx.x >= off) ? s[threadIdx.x - off] : 0;
        __syncthreads();
        s[threadIdx.x] += t;
        __syncthreads();
    }
    if (threadIdx.x < NB) {
        int ex = s[threadIdx.x] - v;
        base[threadIdx.x] = ex;
        cursor[threadIdx.x] = ex;
    }
    if (threadIdx.x == 0) base[NB] = N_EDGES;
}

// ---------------------------------------------------------------------------
// Bin edges into bucket-grouped record array recs[r] = {src, dst}.
// Per-block cursor reservation -> near-sequential writes per bucket window.
// ---------------------------------------------------------------------------
__global__ __launch_bounds__(512) void k_bin(
    const int* __restrict__ ei, int* __restrict__ cursor,
    uint2* __restrict__ recs)
{
    __shared__ int cnt[NB];
    __shared__ int loc[NB];
    __shared__ int cur[NB];
    for (int i = threadIdx.x; i < NB; i += 512) { cnt[i] = 0; cur[i] = 0; }
    __syncthreads();
    int e0 = blockIdx.x * BIN_CHUNK;
    int e1 = min(e0 + BIN_CHUNK, N_EDGES);
    for (int e = e0 + threadIdx.x; e < e1; e += 512)
        atomicAdd(&cnt[ei[N_EDGES + e] >> 7], 1);
    __syncthreads();
    for (int i = threadIdx.x; i < NB; i += 512)
        if (cnt[i] > 0) loc[i] = atomicAdd(&cursor[i], cnt[i]);
    __syncthreads();
    for (int e = e0 + threadIdx.x; e < e1; e += 512) {
        int src = ei[e];
        int dst = ei[N_EDGES + e];
        int bkt = dst >> 7;
        int idx = atomicAdd(&cur[bkt], 1);
        recs[loc[bkt] + idx] = make_uint2((unsigned)src, (unsigned)dst);
    }
}

// ---------------------------------------------------------------------------
// Per-bucket counting sort by (dst & 127): recs -> recs2, globally
// dst-sorted. Two passes over the bucket window (second read hits L2).
// Scatter writes land in the bucket's own 16 KB window (L2-hot).
// ---------------------------------------------------------------------------
__global__ __launch_bounds__(256) void k_sort(
    const int* __restrict__ base, const uint2* __restrict__ recs,
    uint2* __restrict__ recs2)
{
    __shared__ int hist[NPB];
    __shared__ int sc[NPB];
    __shared__ int cur[NPB];
    int b = blockIdx.x;
    int r0 = base[b], r1 = base[b + 1], n = r1 - r0;
    for (int i = threadIdx.x; i < NPB; i += 256) hist[i] = 0;
    __syncthreads();
    for (int i = threadIdx.x; i < n; i += 256)
        atomicAdd(&hist[recs[r0 + i].y & (NPB - 1)], 1);
    __syncthreads();
    if (threadIdx.x < NPB) sc[threadIdx.x] = hist[threadIdx.x];
    __syncthreads();
#pragma unroll
    for (int off = 1; off < NPB; off <<= 1) {
        int t = (threadIdx.x >= off && threadIdx.x < NPB) ? sc[threadIdx.x - off] : 0;
        __syncthreads();
        if (threadIdx.x < NPB) sc[threadIdx.x] += t;
        __syncthreads();
    }
    if (threadIdx.x < NPB) cur[threadIdx.x] = sc[threadIdx.x] - hist[threadIdx.x];
    __syncthreads();
    for (int i = threadIdx.x; i < n; i += 256) {
        uint2 e = recs[r0 + i];
        int slot = atomicAdd(&cur[e.y & (NPB - 1)], 1);
        recs2[r0 + slot] = e;
    }
}

// ---------------------------------------------------------------------------
// Generic 16-dim accumulate over dst-sorted records.
// Each 16-lane group: load ACC_K contiguous recs (broadcast) + ACC_K
// independent 64B line gathers of src_feat, then combine equal-dst runs in
// a register and flush one atomic per run. ~300k atomic transactions total
// (vs 1.6M unsorted) against the ~19 G trans/s memory-side wall.
// ---------------------------------------------------------------------------
__global__ __launch_bounds__(256) void k_acc(
    const uint2* __restrict__ recs,
    const float* __restrict__ src_feat, float* __restrict__ dst_feat)
{
    int w = blockIdx.x * 4 + (threadIdx.x >> 6);    // global wave id
    int s = (threadIdx.x >> 4) & 3;                 // slot within wave
    int f = threadIdx.x & (D_HID - 1);
    int rb = (w * 4 + s) * ACC_K;                   // this group's chunk base

    uint2 e[ACC_K];
#pragma unroll
    for (int k = 0; k < ACC_K; k++) e[k] = recs[rb + k];
    float v[ACC_K];
#pragma unroll
    for (int k = 0; k < ACC_K; k++) v[k] = src_feat[e[k].x * D_HID + f];

    unsigned cur = e[0].y;
    float acc = v[0];
#pragma unroll
    for (int k = 1; k < ACC_K; k++) {
        if (e[k].y == cur) {
            acc += v[k];
        } else {
            atomicAdd(&dst_feat[cur * D_HID + f], acc);
            cur = e[k].y;
            acc = v[k];
        }
    }
    atomicAdd(&dst_feat[cur * D_HID + f], acc);
}

// ---------------------------------------------------------------------------
// h = relu(agg1); re-zero agg1 in place (it becomes the layer-2 accumulator).
// Per-thread row ownership -> read-then-overwrite is race-free.
// ---------------------------------------------------------------------------
__global__ __launch_bounds__(256) void k_node2(
    float* __restrict__ agg, float* __restrict__ h)
{
    int node = blockIdx.x * blockDim.x + threadIdx.x;
    if (node >= N_NODES) return;
    float4* ap = (float4*)(agg + (size_t)node * D_HID);
    float4* hp = (float4*)(h   + (size_t)node * D_HID);
    float4 z = make_float4(0.f, 0.f, 0.f, 0.f);
#pragma unroll
    for (int i = 0; i < D_HID / 4; i++) {
        float4 v = ap[i];
        hp[i] = make_float4(fmaxf(v.x, 0.f), fmaxf(v.y, 0.f),
                            fmaxf(v.z, 0.f), fmaxf(v.w, 0.f));
        ap[i] = z;
    }
}

// ---------------------------------------------------------------------------
// Final epilogue: out = aggH @ w2_rel^T + h @ w2_root^T + b2.
// ---------------------------------------------------------------------------
__global__ __launch_bounds__(256) void k_out(
    const float* __restrict__ h, const float* __restrict__ aggh,
    const float* __restrict__ w_rel, const float* __restrict__ w_root,
    const float* __restrict__ b, float* __restrict__ outv)
{
    __shared__ float s_rel[D_OUT * D_HID];
    __shared__ float s_root[D_OUT * D_HID];
    __shared__ float s_b[D_OUT];
    if (threadIdx.x < D_OUT * D_HID) {
        s_rel[threadIdx.x]  = w_rel[threadIdx.x];
        s_root[threadIdx.x] = w_root[threadIdx.x];
    }
    if (threadIdx.x < D_OUT) s_b[threadIdx.x] = b[threadIdx.x];
    __syncthreads();

    int node = blockIdx.x * blockDim.x + threadIdx.x;
    if (node >= N_NODES) return;

    float hv[D_HID], av[D_HID];
    const float4* hp = (const float4*)(h    + (size_t)node * D_HID);
    const float4* ap = (const float4*)(aggh + (size_t)node * D_HID);
#pragma unroll
    for (int i = 0; i < D_HID / 4; i++) {
        float4 a = hp[i];
        hv[4*i+0] = a.x; hv[4*i+1] = a.y; hv[4*i+2] = a.z; hv[4*i+3] = a.w;
        float4 c = ap[i];
        av[4*i+0] = c.x; av[4*i+1] = c.y; av[4*i+2] = c.z; av[4*i+3] = c.w;
    }

    float o[D_OUT];
#pragma unroll
    for (int oo = 0; oo < D_OUT; oo++) {
        float r = s_b[oo];
#pragma unroll
        for (int k = 0; k < D_HID; k++)
            r += av[k] * s_rel[oo * D_HID + k] + hv[k] * s_root[oo * D_HID + k];
        o[oo] = r;
    }
    ((float2*)(outv + (size_t)node * D_OUT))[0] = make_float2(o[0], o[1]);
}

extern "C" void kernel_launch(void* const* d_in, const int* in_sizes, int n_in,
                              void* d_out, int out_size, void* d_ws, size_t ws_size,
                              hipStream_t stream) {
    const float* x       = (const float*)d_in[0];
    const int*   ei      = (const int*)  d_in[1];
    const float* w1_rel  = (const float*)d_in[2];
    const float* w1_root = (const float*)d_in[3];
    const float* b1      = (const float*)d_in[4];
    const float* w2_rel  = (const float*)d_in[5];
    const float* w2_root = (const float*)d_in[6];
    const float* b2      = (const float*)d_in[7];
    float* out = (float*)d_out;

    // Workspace (~25.7 MB) with time-multiplexed region A:
    //   [0 .. 12.8 MB):  phase 1: recs_raw (E uint2)
    //                    phase 2: xr (N*16 f) | agg (N*16 f)
    //                    phase 3: h  (aliases xr) | agg2 (aliases agg)
    //   [12.8 .. 25.6):  recs2 (dst-sorted records)
    //   tail: gdeg[NB], base[NB+1], cursor[NB]
    float* xr   = (float*)d_ws;
    float* agg  = xr + (size_t)N_NODES * D_HID;
    float* h    = xr;                                   // alias (xr dead by then)
    uint2* recs_raw = (uint2*)d_ws;                     // alias (dead before xr)
    uint2* recs2    = (uint2*)(xr + 3200000);
    int*   gdeg   = (int*)(recs2 + N_EDGES);
    int*   base   = gdeg + NB;
    int*   cursor = base + NB + 1;

    hipMemsetAsync(gdeg, 0, NB * sizeof(int), stream);

    k_histb<<<dim3(HIST_BLOCKS), dim3(512), 0, stream>>>(ei, gdeg);

    k_scan<<<dim3(1), dim3(1024), 0, stream>>>(gdeg, base, cursor);

    k_bin<<<dim3(BIN_BLOCKS), dim3(512), 0, stream>>>(ei, cursor, recs_raw);

    k_sort<<<dim3(NB), dim3(256), 0, stream>>>(base, recs_raw, recs2);

    // recs_raw dead; region A becomes xr | agg.
    k_node1<<<dim3((N_NODES + 255) / 256), dim3(256), 0, stream>>>(
        x, w1_rel, w1_root, b1, xr, agg);

    k_acc<<<dim3(ACC_BLOCKS), dim3(256), 0, stream>>>(recs2, xr, agg);

    // h = relu(agg); agg re-zeroed as layer-2 accumulator.
    k_node2<<<dim3((N_NODES + 255) / 256), dim3(256), 0, stream>>>(agg, h);

    k_acc<<<dim3(ACC_BLOCKS), dim3(256), 0, stream>>>(recs2, h, agg);

    k_out<<<dim3((N_NODES + 255) / 256), dim3(256), 0, stream>>>(
        h, agg, w2_rel, w2_root, b2, out);
}

// Round 7
// 225.242 us; speedup vs baseline: 1.4710x; 1.0500x over previous
//
#include <hip/hip_runtime.h>

#define N_NODES 100000
#define N_EDGES 1600000
#define D_IN 32
#define D_HID 16
#define D_OUT 2

// dst bucketing: 128 nodes per bucket.
#define NPB 128
#define NB 782                                                // ceil(100000/128)
#define BIN_CHUNK 4096
#define BIN_BLOCKS ((N_EDGES + BIN_CHUNK - 1) / BIN_CHUNK)    // 391
#define MSCAN_CHUNKS ((BIN_BLOCKS + 63) / 64)                 // 7

// Accumulate kernel: each 16-lane group owns a contiguous chunk of ACC_K
// records; a wave covers 4*ACC_K records. 1.6M / 32 = 50000 waves exactly.
#define ACC_K 8
#define ACC_BLOCKS (N_EDGES / (4 * ACC_K) / 4)                // 12500

// ---------------------------------------------------------------------------
// Per-node dense transforms for layer 1.
//   xr[i]  = x[i] @ w1_rel^T     (gathered over edges later)
//   agg[i] = x[i] @ w1_root^T + b1   (atomic accumulator pre-init with root)
// ---------------------------------------------------------------------------
__global__ __launch_bounds__(256) void k_node1(
    const float* __restrict__ x,
    const float* __restrict__ w_rel, const float* __restrict__ w_root,
    const float* __restrict__ b,
    float* __restrict__ xr, float* __restrict__ agg)
{
    __shared__ float s_rel[D_HID * D_IN];
    __shared__ float s_root[D_HID * D_IN];
    __shared__ float s_b[D_HID];
    for (int i = threadIdx.x; i < D_HID * D_IN; i += blockDim.x) {
        s_rel[i]  = w_rel[i];
        s_root[i] = w_root[i];
    }
    if (threadIdx.x < D_HID) s_b[threadIdx.x] = b[threadIdx.x];
    __syncthreads();

    int node = blockIdx.x * blockDim.x + threadIdx.x;
    if (node >= N_NODES) return;

    float row[D_IN];
    const float4* xp = (const float4*)(x + (size_t)node * D_IN);
#pragma unroll
    for (int i = 0; i < D_IN / 4; i++) {
        float4 v = xp[i];
        row[4*i+0] = v.x; row[4*i+1] = v.y; row[4*i+2] = v.z; row[4*i+3] = v.w;
    }

    float oa[D_HID], orr[D_HID];
#pragma unroll
    for (int o = 0; o < D_HID; o++) {
        float a = 0.f, r = s_b[o];
#pragma unroll
        for (int k = 0; k < D_IN; k++) {
            a += row[k] * s_rel[o * D_IN + k];
            r += row[k] * s_root[o * D_IN + k];
        }
        oa[o] = a; orr[o] = r;
    }

    float4* xrp  = (float4*)(xr  + (size_t)node * D_HID);
    float4* aggp = (float4*)(agg + (size_t)node * D_HID);
#pragma unroll
    for (int i = 0; i < D_HID / 4; i++) {
        xrp[i]  = make_float4(oa[4*i], oa[4*i+1], oa[4*i+2], oa[4*i+3]);
        aggp[i] = make_float4(orr[4*i], orr[4*i+1], orr[4*i+2], orr[4*i+3]);
    }
}

// ---------------------------------------------------------------------------
// Counting-sort pass A: per-block bucket histogram -> cnt[b][j] (coalesced).
// No global atomics.
// ---------------------------------------------------------------------------
__global__ __launch_bounds__(512) void k_cnt(
    const int* __restrict__ ei, int* __restrict__ cnt)
{
    __shared__ int h[NB];
    for (int i = threadIdx.x; i < NB; i += 512) h[i] = 0;
    __syncthreads();
    int e0 = blockIdx.x * BIN_CHUNK;
    int e1 = min(e0 + BIN_CHUNK, N_EDGES);
    for (int e = e0 + threadIdx.x; e < e1; e += 512)
        atomicAdd(&h[ei[N_EDGES + e] >> 7], 1);
    __syncthreads();
    for (int i = threadIdx.x; i < NB; i += 512)
        cnt[blockIdx.x * NB + i] = h[i];
}

// ---------------------------------------------------------------------------
// Counting-sort pass B: per-bucket exclusive scan over blocks.
// One wave per bucket; shuffle-scan 64 blocks per chunk.
//   offs[b][j] = sum_{b'<b} cnt[b'][j];  tot[j] = column total.
// ---------------------------------------------------------------------------
__global__ __launch_bounds__(256) void k_mscan(
    const int* __restrict__ cnt, int* __restrict__ offs, int* __restrict__ tot)
{
    int w = blockIdx.x * 4 + (threadIdx.x >> 6);    // bucket id (wave-uniform)
    int lane = threadIdx.x & 63;
    if (w >= NB) return;
    int running = 0;
    for (int c = 0; c < MSCAN_CHUNKS; c++) {
        int b = c * 64 + lane;
        int v = (b < BIN_BLOCKS) ? cnt[b * NB + w] : 0;
        int incl = v;
#pragma unroll
        for (int off = 1; off < 64; off <<= 1) {
            int t = __shfl_up(incl, off);
            if (lane >= off) incl += t;
        }
        if (b < BIN_BLOCKS) offs[b * NB + w] = running + incl - v;
        running += __shfl(incl, 63);
    }
    if (lane == 0) tot[w] = running;
}

// ---------------------------------------------------------------------------
// Exclusive scan of the NB bucket totals -> base[]; base[NB] = E.
// ---------------------------------------------------------------------------
__global__ __launch_bounds__(1024) void k_scan(
    const int* __restrict__ tot, int* __restrict__ base)
{
    __shared__ int s[1024];
    int v = (threadIdx.x < NB) ? tot[threadIdx.x] : 0;
    s[threadIdx.x] = v;
    __syncthreads();
#pragma unroll
    for (int off = 1; off < 1024; off <<= 1) {
        int t = (threadIdx.x >= off) ? s[threadIdx.x - off] : 0;
        __syncthreads();
        s[threadIdx.x] += t;
        __syncthreads();
    }
    if (threadIdx.x < NB) base[threadIdx.x] = s[threadIdx.x] - v;
    if (threadIdx.x == 0) base[NB] = N_EDGES;
}

// ---------------------------------------------------------------------------
// Counting-sort pass C: scatter edges into bucket-grouped recs[] using
// exact per-(block,bucket) offsets. LDS cursors only — no global atomics.
// ---------------------------------------------------------------------------
__global__ __launch_bounds__(512) void k_bin2(
    const int* __restrict__ ei, const int* __restrict__ offs,
    const int* __restrict__ base, uint2* __restrict__ recs)
{
    __shared__ int cur[NB];
    for (int i = threadIdx.x; i < NB; i += 512)
        cur[i] = offs[blockIdx.x * NB + i] + base[i];
    __syncthreads();
    int e0 = blockIdx.x * BIN_CHUNK;
    int e1 = min(e0 + BIN_CHUNK, N_EDGES);
    for (int e = e0 + threadIdx.x; e < e1; e += 512) {
        int src = ei[e];
        int dst = ei[N_EDGES + e];
        int idx = atomicAdd(&cur[dst >> 7], 1);
        recs[idx] = make_uint2((unsigned)src, (unsigned)dst);
    }
}

// ---------------------------------------------------------------------------
// Per-bucket counting sort by (dst & 127): recs -> recs2, globally
// dst-sorted. Scatter writes land in the bucket's 16 KB window (L2-hot).
// ---------------------------------------------------------------------------
__global__ __launch_bounds__(256) void k_sort(
    const int* __restrict__ base, const uint2* __restrict__ recs,
    uint2* __restrict__ recs2)
{
    __shared__ int hist[NPB];
    __shared__ int sc[NPB];
    __shared__ int cur[NPB];
    int b = blockIdx.x;
    int r0 = base[b], r1 = base[b + 1], n = r1 - r0;
    for (int i = threadIdx.x; i < NPB; i += 256) hist[i] = 0;
    __syncthreads();
    for (int i = threadIdx.x; i < n; i += 256)
        atomicAdd(&hist[recs[r0 + i].y & (NPB - 1)], 1);
    __syncthreads();
    if (threadIdx.x < NPB) sc[threadIdx.x] = hist[threadIdx.x];
    __syncthreads();
#pragma unroll
    for (int off = 1; off < NPB; off <<= 1) {
        int t = (threadIdx.x >= off && threadIdx.x < NPB) ? sc[threadIdx.x - off] : 0;
        __syncthreads();
        if (threadIdx.x < NPB) sc[threadIdx.x] += t;
        __syncthreads();
    }
    if (threadIdx.x < NPB) cur[threadIdx.x] = sc[threadIdx.x] - hist[threadIdx.x];
    __syncthreads();
    for (int i = threadIdx.x; i < n; i += 256) {
        uint2 e = recs[r0 + i];
        int slot = atomicAdd(&cur[e.y & (NPB - 1)], 1);
        recs2[r0 + slot] = e;
    }
}

// ---------------------------------------------------------------------------
// Generic 16-dim accumulate over dst-sorted records.
// Each 16-lane group: load ACC_K contiguous recs + ACC_K independent 64B
// line gathers, combine equal-dst runs in registers, one atomic per run
// (~300k atomic transactions vs 1.6M unsorted).
// ---------------------------------------------------------------------------
__global__ __launch_bounds__(256) void k_acc(
    const uint2* __restrict__ recs,
    const float* __restrict__ src_feat, float* __restrict__ dst_feat)
{
    int w = blockIdx.x * 4 + (threadIdx.x >> 6);    // global wave id
    int s = (threadIdx.x >> 4) & 3;                 // slot within wave
    int f = threadIdx.x & (D_HID - 1);
    int rb = (w * 4 + s) * ACC_K;                   // this group's chunk base

    uint2 e[ACC_K];
#pragma unroll
    for (int k = 0; k < ACC_K; k++) e[k] = recs[rb + k];
    float v[ACC_K];
#pragma unroll
    for (int k = 0; k < ACC_K; k++) v[k] = src_feat[e[k].x * D_HID + f];

    unsigned cur = e[0].y;
    float acc = v[0];
#pragma unroll
    for (int k = 1; k < ACC_K; k++) {
        if (e[k].y == cur) {
            acc += v[k];
        } else {
            atomicAdd(&dst_feat[cur * D_HID + f], acc);
            cur = e[k].y;
            acc = v[k];
        }
    }
    atomicAdd(&dst_feat[cur * D_HID + f], acc);
}

// ---------------------------------------------------------------------------
// h = relu(agg1); re-zero agg1 in place (it becomes the layer-2 accumulator).
// Per-thread row ownership -> read-then-overwrite is race-free.
// ---------------------------------------------------------------------------
__global__ __launch_bounds__(256) void k_node2(
    float* __restrict__ agg, float* __restrict__ h)
{
    int node = blockIdx.x * blockDim.x + threadIdx.x;
    if (node >= N_NODES) return;
    float4* ap = (float4*)(agg + (size_t)node * D_HID);
    float4* hp = (float4*)(h   + (size_t)node * D_HID);
    float4 z = make_float4(0.f, 0.f, 0.f, 0.f);
#pragma unroll
    for (int i = 0; i < D_HID / 4; i++) {
        float4 v = ap[i];
        hp[i] = make_float4(fmaxf(v.x, 0.f), fmaxf(v.y, 0.f),
                            fmaxf(v.z, 0.f), fmaxf(v.w, 0.f));
        ap[i] = z;
    }
}

// ---------------------------------------------------------------------------
// Final epilogue: out = aggH @ w2_rel^T + h @ w2_root^T + b2.
// ---------------------------------------------------------------------------
__global__ __launch_bounds__(256) void k_out(
    const float* __restrict__ h, const float* __restrict__ aggh,
    const float* __restrict__ w_rel, const float* __restrict__ w_root,
    const float* __restrict__ b, float* __restrict__ outv)
{
    __shared__ float s_rel[D_OUT * D_HID];
    __shared__ float s_root[D_OUT * D_HID];
    __shared__ float s_b[D_OUT];
    if (threadIdx.x < D_OUT * D_HID) {
        s_rel[threadIdx.x]  = w_rel[threadIdx.x];
        s_root[threadIdx.x] = w_root[threadIdx.x];
    }
    if (threadIdx.x < D_OUT) s_b[threadIdx.x] = b[threadIdx.x];
    __syncthreads();

    int node = blockIdx.x * blockDim.x + threadIdx.x;
    if (node >= N_NODES) return;

    float hv[D_HID], av[D_HID];
    const float4* hp = (const float4*)(h    + (size_t)node * D_HID);
    const float4* ap = (const float4*)(aggh + (size_t)node * D_HID);
#pragma unroll
    for (int i = 0; i < D_HID / 4; i++) {
        float4 a = hp[i];
        hv[4*i+0] = a.x; hv[4*i+1] = a.y; hv[4*i+2] = a.z; hv[4*i+3] = a.w;
        float4 c = ap[i];
        av[4*i+0] = c.x; av[4*i+1] = c.y; av[4*i+2] = c.z; av[4*i+3] = c.w;
    }

    float o[D_OUT];
#pragma unroll
    for (int oo = 0; oo < D_OUT; oo++) {
        float r = s_b[oo];
#pragma unroll
        for (int k = 0; k < D_HID; k++)
            r += av[k] * s_rel[oo * D_HID + k] + hv[k] * s_root[oo * D_HID + k];
        o[oo] = r;
    }
    ((float2*)(outv + (size_t)node * D_OUT))[0] = make_float2(o[0], o[1]);
}

extern "C" void kernel_launch(void* const* d_in, const int* in_sizes, int n_in,
                              void* d_out, int out_size, void* d_ws, size_t ws_size,
                              hipStream_t stream) {
    const float* x       = (const float*)d_in[0];
    const int*   ei      = (const int*)  d_in[1];
    const float* w1_rel  = (const float*)d_in[2];
    const float* w1_root = (const float*)d_in[3];
    const float* b1      = (const float*)d_in[4];
    const float* w2_rel  = (const float*)d_in[5];
    const float* w2_root = (const float*)d_in[6];
    const float* b2      = (const float*)d_in[7];
    float* out = (float*)d_out;

    // Workspace (~28.2 MB) with time-multiplexed region A:
    //   [0 .. 12.8 MB):  phase 1: recs_raw (E uint2)
    //                    phase 2: xr (N*16 f) | agg (N*16 f); h aliases xr
    //   [12.8 .. 25.6):  recs2 (dst-sorted records)
    //   tail: cnt[B*NB], offs[B*NB], tot[NB], base[NB+1]
    float* xr   = (float*)d_ws;
    float* agg  = xr + (size_t)N_NODES * D_HID;
    float* h    = xr;                                   // alias (xr dead by then)
    uint2* recs_raw = (uint2*)d_ws;                     // alias (dead before xr)
    uint2* recs2    = (uint2*)(xr + 3200000);
    int*   cnt  = (int*)(recs2 + N_EDGES);              // BIN_BLOCKS*NB
    int*   offs = cnt + BIN_BLOCKS * NB;                // BIN_BLOCKS*NB
    int*   tot  = offs + BIN_BLOCKS * NB;               // NB
    int*   base = tot + NB;                             // NB+1

    k_cnt<<<dim3(BIN_BLOCKS), dim3(512), 0, stream>>>(ei, cnt);

    k_mscan<<<dim3((NB + 3) / 4), dim3(256), 0, stream>>>(cnt, offs, tot);

    k_scan<<<dim3(1), dim3(1024), 0, stream>>>(tot, base);

    k_bin2<<<dim3(BIN_BLOCKS), dim3(512), 0, stream>>>(ei, offs, base, recs_raw);

    k_sort<<<dim3(NB), dim3(256), 0, stream>>>(base, recs_raw, recs2);

    // recs_raw dead; region A becomes xr | agg.
    k_node1<<<dim3((N_NODES + 255) / 256), dim3(256), 0, stream>>>(
        x, w1_rel, w1_root, b1, xr, agg);

    k_acc<<<dim3(ACC_BLOCKS), dim3(256), 0, stream>>>(recs2, xr, agg);

    // h = relu(agg); agg re-zeroed as layer-2 accumulator.
    k_node2<<<dim3((N_NODES + 255) / 256), dim3(256), 0, stream>>>(agg, h);

    k_acc<<<dim3(ACC_BLOCKS), dim3(256), 0, stream>>>(recs2, h, agg);

    k_out<<<dim3((N_NODES + 255) / 256), dim3(256), 0, stream>>>(
        h, agg, w2_rel, w2_root, b2, out);
}

// Round 8
// 218.419 us; speedup vs baseline: 1.5169x; 1.0312x over previous
//
#include <hip/hip_runtime.h>

#define N_NODES 100000
#define N_EDGES 1600000
#define D_IN 32
#define D_HID 16
#define D_OUT 2

// dst bucketing: 128 nodes per bucket.
#define NPB 128
#define NB 782                                                // ceil(100000/128)
#define NROWS (NB * NPB)                                      // 100096 padded rows
#define BIN_CHUNK 4096
#define BIN_BLOCKS ((N_EDGES + BIN_CHUNK - 1) / BIN_CHUNK)    // 391
#define MSCAN_CHUNKS ((BIN_BLOCKS + 63) / 64)                 // 7

// Padded sorted-record layout: PBC slots per bucket (mean fill 2046, 11 sigma).
#define PBC 2560
#define SORT_CAP 2816                                         // LDS stage cap
#define DUMMY_SRC 100000u                                     // zeroed feature row
#define DUMMY_REC ((127u << 17) | DUMMY_SRC)

// k_acc: 16 lanes per record, ACC_K records per group, 16 groups per block.
#define ACC_K 8
#define ACC_BPB (PBC / (ACC_K * 16))                          // 20 blocks per bucket
#define ACC_BLOCKS (NB * ACC_BPB)                             // 15640

__device__ __forceinline__ unsigned bfr(float x) {            // f32 -> bf16 (RNE)
    unsigned u = __float_as_uint(x);
    return (u + 0x7FFFu + ((u >> 16) & 1u)) >> 16;
}
__device__ __forceinline__ float bfu(unsigned lo16) {         // bf16 bits -> f32
    return __uint_as_float(lo16 << 16);
}

// ---------------------------------------------------------------------------
// Per-node dense transforms for layer 1.
//   xr[i] (bf16) = x[i] @ w1_rel^T ;  agg[i] (f32) = x[i] @ w1_root^T + b1
// node == N_NODES writes the zero dummy row of xr only.
// ---------------------------------------------------------------------------
__global__ __launch_bounds__(256) void k_node1(
    const float* __restrict__ x,
    const float* __restrict__ w_rel, const float* __restrict__ w_root,
    const float* __restrict__ b,
    unsigned short* __restrict__ xr, float* __restrict__ agg)
{
    __shared__ float s_rel[D_HID * D_IN];
    __shared__ float s_root[D_HID * D_IN];
    __shared__ float s_b[D_HID];
    for (int i = threadIdx.x; i < D_HID * D_IN; i += blockDim.x) {
        s_rel[i]  = w_rel[i];
        s_root[i] = w_root[i];
    }
    if (threadIdx.x < D_HID) s_b[threadIdx.x] = b[threadIdx.x];
    __syncthreads();

    int node = blockIdx.x * blockDim.x + threadIdx.x;
    if (node > N_NODES) return;
    if (node == N_NODES) {                       // dummy zero row
        uint4* xp = (uint4*)(xr + (size_t)node * D_HID);
        xp[0] = make_uint4(0, 0, 0, 0);
        xp[1] = make_uint4(0, 0, 0, 0);
        return;
    }

    float row[D_IN];
    const float4* xp = (const float4*)(x + (size_t)node * D_IN);
#pragma unroll
    for (int i = 0; i < D_IN / 4; i++) {
        float4 v = xp[i];
        row[4*i+0] = v.x; row[4*i+1] = v.y; row[4*i+2] = v.z; row[4*i+3] = v.w;
    }

    float oa[D_HID], orr[D_HID];
#pragma unroll
    for (int o = 0; o < D_HID; o++) {
        float a = 0.f, r = s_b[o];
#pragma unroll
        for (int k = 0; k < D_IN; k++) {
            a += row[k] * s_rel[o * D_IN + k];
            r += row[k] * s_root[o * D_IN + k];
        }
        oa[o] = a; orr[o] = r;
    }

    unsigned p[8];
#pragma unroll
    for (int i = 0; i < 8; i++)
        p[i] = bfr(oa[2*i]) | (bfr(oa[2*i+1]) << 16);
    uint4* xrp = (uint4*)(xr + (size_t)node * D_HID);
    xrp[0] = make_uint4(p[0], p[1], p[2], p[3]);
    xrp[1] = make_uint4(p[4], p[5], p[6], p[7]);

    float4* aggp = (float4*)(agg + (size_t)node * D_HID);
#pragma unroll
    for (int i = 0; i < D_HID / 4; i++)
        aggp[i] = make_float4(orr[4*i], orr[4*i+1], orr[4*i+2], orr[4*i+3]);
}

// ---------------------------------------------------------------------------
// Counting-sort pass A: per-block bucket histogram -> cnt[b][j] (coalesced).
// ---------------------------------------------------------------------------
__global__ __launch_bounds__(512) void k_cnt(
    const int* __restrict__ ei, int* __restrict__ cnt)
{
    __shared__ int h[NB];
    for (int i = threadIdx.x; i < NB; i += 512) h[i] = 0;
    __syncthreads();
    int e0 = blockIdx.x * BIN_CHUNK;
    int e1 = min(e0 + BIN_CHUNK, N_EDGES);
    for (int e = e0 + threadIdx.x; e < e1; e += 512)
        atomicAdd(&h[ei[N_EDGES + e] >> 7], 1);
    __syncthreads();
    for (int i = threadIdx.x; i < NB; i += 512)
        cnt[blockIdx.x * NB + i] = h[i];
}

// ---------------------------------------------------------------------------
// Counting-sort pass B: per-bucket exclusive scan over blocks (1 wave/bucket).
// ---------------------------------------------------------------------------
__global__ __launch_bounds__(256) void k_mscan(
    const int* __restrict__ cnt, int* __restrict__ offs, int* __restrict__ tot)
{
    int w = blockIdx.x * 4 + (threadIdx.x >> 6);
    int lane = threadIdx.x & 63;
    if (w >= NB) return;
    int running = 0;
    for (int c = 0; c < MSCAN_CHUNKS; c++) {
        int b = c * 64 + lane;
        int v = (b < BIN_BLOCKS) ? cnt[b * NB + w] : 0;
        int incl = v;
#pragma unroll
        for (int off = 1; off < 64; off <<= 1) {
            int t = __shfl_up(incl, off);
            if (lane >= off) incl += t;
        }
        if (b < BIN_BLOCKS) offs[b * NB + w] = running + incl - v;
        running += __shfl(incl, 63);
    }
    if (lane == 0) tot[w] = running;
}

// ---------------------------------------------------------------------------
// Exclusive scan of the NB bucket totals -> base[]; base[NB] = E.
// ---------------------------------------------------------------------------
__global__ __launch_bounds__(1024) void k_scan(
    const int* __restrict__ tot, int* __restrict__ base)
{
    __shared__ int s[1024];
    int v = (threadIdx.x < NB) ? tot[threadIdx.x] : 0;
    s[threadIdx.x] = v;
    __syncthreads();
#pragma unroll
    for (int off = 1; off < 1024; off <<= 1) {
        int t = (threadIdx.x >= off) ? s[threadIdx.x - off] : 0;
        __syncthreads();
        s[threadIdx.x] += t;
        __syncthreads();
    }
    if (threadIdx.x < NB) base[threadIdx.x] = s[threadIdx.x] - v;
    if (threadIdx.x == 0) base[NB] = N_EDGES;
}

// ---------------------------------------------------------------------------
// Counting-sort pass C: scatter edges as packed 4 B records into
// bucket-grouped recs_raw[] using exact per-(block,bucket) offsets.
// rec = (dst&127)<<17 | src.
// ---------------------------------------------------------------------------
__global__ __launch_bounds__(512) void k_bin2(
    const int* __restrict__ ei, const int* __restrict__ offs,
    const int* __restrict__ base, unsigned* __restrict__ recs)
{
    __shared__ int cur[NB];
    for (int i = threadIdx.x; i < NB; i += 512)
        cur[i] = offs[blockIdx.x * NB + i] + base[i];
    __syncthreads();
    int e0 = blockIdx.x * BIN_CHUNK;
    int e1 = min(e0 + BIN_CHUNK, N_EDGES);
    for (int e = e0 + threadIdx.x; e < e1; e += 512) {
        int src = ei[e];
        int dst = ei[N_EDGES + e];
        int idx = atomicAdd(&cur[dst >> 7], 1);
        recs[idx] = ((unsigned)(dst & (NPB - 1)) << 17) | (unsigned)src;
    }
}

// ---------------------------------------------------------------------------
// Per-bucket counting sort by dl: LDS-staged single global read, write into
// the bucket's block-exclusive padded window; pad tail to ACC_K with dummies.
// ---------------------------------------------------------------------------
__global__ __launch_bounds__(256) void k_sort(
    const int* __restrict__ base, const unsigned* __restrict__ recs,
    unsigned* __restrict__ recs2)
{
    __shared__ unsigned stage[SORT_CAP];
    __shared__ int hist[NPB];
    __shared__ int sc[NPB];
    __shared__ int cur[NPB];
    int b = blockIdx.x;
    int r0 = base[b];
    int n = base[b + 1] - r0;
    if (n > PBC) n = PBC;                        // 11-sigma guard
    for (int i = threadIdx.x; i < NPB; i += 256) hist[i] = 0;
    for (int i = threadIdx.x; i < n; i += 256) stage[i] = recs[r0 + i];
    __syncthreads();
    for (int i = threadIdx.x; i < n; i += 256)
        atomicAdd(&hist[stage[i] >> 17], 1);
    __syncthreads();
    if (threadIdx.x < NPB) sc[threadIdx.x] = hist[threadIdx.x];
    __syncthreads();
#pragma unroll
    for (int off = 1; off < NPB; off <<= 1) {
        int t = (threadIdx.x >= off && threadIdx.x < NPB) ? sc[threadIdx.x - off] : 0;
        __syncthreads();
        if (threadIdx.x < NPB) sc[threadIdx.x] += t;
        __syncthreads();
    }
    if (threadIdx.x < NPB) cur[threadIdx.x] = sc[threadIdx.x] - hist[threadIdx.x];
    __syncthreads();
    unsigned* w = recs2 + (size_t)b * PBC;
    for (int i = threadIdx.x; i < n; i += 256) {
        unsigned r = stage[i];
        int slot = atomicAdd(&cur[r >> 17], 1);
        w[slot] = r;
    }
    int npad = (n + ACC_K - 1) & ~(ACC_K - 1);
    for (int i = n + threadIdx.x; i < npad; i += 256) w[i] = DUMMY_REC;
}

// ---------------------------------------------------------------------------
// Generic 16-dim accumulate over dst-sorted padded records, bf16 sources.
// 16 lanes/record, ACC_K records/group, run-combining, 1 atomic line/run.
// dst = bucket*128 + (rec>>17); sources L2-resident (3.2 MB bf16).
// ---------------------------------------------------------------------------
__global__ __launch_bounds__(256) void k_acc(
    const unsigned* __restrict__ recs2, const int* __restrict__ tot,
    const unsigned short* __restrict__ srcf, float* __restrict__ dstf)
{
    int bucket = blockIdx.x / ACC_BPB;
    int blk    = blockIdx.x % ACC_BPB;
    int g = threadIdx.x >> 4;
    int f = threadIdx.x & (D_HID - 1);
    int r0 = (blk * 16 + g) * ACC_K;
    int n = tot[bucket];
    if (r0 >= n) return;
    const unsigned* rp = recs2 + (size_t)bucket * PBC + r0;

    unsigned e[ACC_K];
#pragma unroll
    for (int k = 0; k < ACC_K; k++) e[k] = rp[k];
    float v[ACC_K];
#pragma unroll
    for (int k = 0; k < ACC_K; k++)
        v[k] = bfu(srcf[(e[k] & 0x1FFFF) * D_HID + f]);

    int dbase = bucket * NPB;
    unsigned cur = e[0] >> 17;
    float acc = v[0];
#pragma unroll
    for (int k = 1; k < ACC_K; k++) {
        unsigned dl = e[k] >> 17;
        if (dl == cur) {
            acc += v[k];
        } else {
            atomicAdd(&dstf[(dbase + cur) * D_HID + f], acc);
            cur = dl;
            acc = v[k];
        }
    }
    atomicAdd(&dstf[(dbase + cur) * D_HID + f], acc);
}

// ---------------------------------------------------------------------------
// h = relu(agg1) as bf16; re-zero agg1 (becomes the layer-2 accumulator).
// node == N_NODES writes the zero dummy row of h only.
// ---------------------------------------------------------------------------
__global__ __launch_bounds__(256) void k_node2(
    float* __restrict__ agg, unsigned short* __restrict__ h)
{
    int node = blockIdx.x * blockDim.x + threadIdx.x;
    if (node > N_NODES) return;
    uint4* hp = (uint4*)(h + (size_t)node * D_HID);
    if (node == N_NODES) {
        hp[0] = make_uint4(0, 0, 0, 0);
        hp[1] = make_uint4(0, 0, 0, 0);
        return;
    }
    float4* ap = (float4*)(agg + (size_t)node * D_HID);
    float hv[D_HID];
#pragma unroll
    for (int i = 0; i < D_HID / 4; i++) {
        float4 v = ap[i];
        hv[4*i+0] = fmaxf(v.x, 0.f); hv[4*i+1] = fmaxf(v.y, 0.f);
        hv[4*i+2] = fmaxf(v.z, 0.f); hv[4*i+3] = fmaxf(v.w, 0.f);
        ap[i] = make_float4(0.f, 0.f, 0.f, 0.f);
    }
    unsigned p[8];
#pragma unroll
    for (int i = 0; i < 8; i++)
        p[i] = bfr(hv[2*i]) | (bfr(hv[2*i+1]) << 16);
    hp[0] = make_uint4(p[0], p[1], p[2], p[3]);
    hp[1] = make_uint4(p[4], p[5], p[6], p[7]);
}

// ---------------------------------------------------------------------------
// Final epilogue: out = aggH @ w2_rel^T + h @ w2_root^T + b2  (h is bf16).
// ---------------------------------------------------------------------------
__global__ __launch_bounds__(256) void k_out(
    const unsigned short* __restrict__ h, const float* __restrict__ aggh,
    const float* __restrict__ w_rel, const float* __restrict__ w_root,
    const float* __restrict__ b, float* __restrict__ outv)
{
    __shared__ float s_rel[D_OUT * D_HID];
    __shared__ float s_root[D_OUT * D_HID];
    __shared__ float s_b[D_OUT];
    if (threadIdx.x < D_OUT * D_HID) {
        s_rel[threadIdx.x]  = w_rel[threadIdx.x];
        s_root[threadIdx.x] = w_root[threadIdx.x];
    }
    if (threadIdx.x < D_OUT) s_b[threadIdx.x] = b[threadIdx.x];
    __syncthreads();

    int node = blockIdx.x * blockDim.x + threadIdx.x;
    if (node >= N_NODES) return;

    const uint4* hp = (const uint4*)(h + (size_t)node * D_HID);
    uint4 h0 = hp[0], h1 = hp[1];
    unsigned pk[8] = {h0.x, h0.y, h0.z, h0.w, h1.x, h1.y, h1.z, h1.w};
    float hv[D_HID];
#pragma unroll
    for (int i = 0; i < 8; i++) {
        hv[2*i]   = bfu(pk[i] & 0xFFFFu);
        hv[2*i+1] = __uint_as_float(pk[i] & 0xFFFF0000u);
    }

    float av[D_HID];
    const float4* ap = (const float4*)(aggh + (size_t)node * D_HID);
#pragma unroll
    for (int i = 0; i < D_HID / 4; i++) {
        float4 c = ap[i];
        av[4*i+0] = c.x; av[4*i+1] = c.y; av[4*i+2] = c.z; av[4*i+3] = c.w;
    }

    float o[D_OUT];
#pragma unroll
    for (int oo = 0; oo < D_OUT; oo++) {
        float r = s_b[oo];
#pragma unroll
        for (int k = 0; k < D_HID; k++)
            r += av[k] * s_rel[oo * D_HID + k] + hv[k] * s_root[oo * D_HID + k];
        o[oo] = r;
    }
    ((float2*)(outv + (size_t)node * D_OUT))[0] = make_float2(o[0], o[1]);
}

extern "C" void kernel_launch(void* const* d_in, const int* in_sizes, int n_in,
                              void* d_out, int out_size, void* d_ws, size_t ws_size,
                              hipStream_t stream) {
    const float* x       = (const float*)d_in[0];
    const int*   ei      = (const int*)  d_in[1];
    const float* w1_rel  = (const float*)d_in[2];
    const float* w1_root = (const float*)d_in[3];
    const float* b1      = (const float*)d_in[4];
    const float* w2_rel  = (const float*)d_in[5];
    const float* w2_root = (const float*)d_in[6];
    const float* b2      = (const float*)d_in[7];
    float* out = (float*)d_out;

    // Workspace (~25.3 MB, no aliasing; everything rewritten each call):
    float*          agg   = (float*)d_ws;                       // NROWS*16 f32 (6.4 MB)
    unsigned short* xrh   = (unsigned short*)(agg + (size_t)NROWS * D_HID); // (N+1)*16 bf16 (3.2 MB)
    unsigned*       recsr = (unsigned*)(xrh + (size_t)(N_NODES + 8) * D_HID); // E (6.4 MB)
    unsigned*       recs2 = recsr + N_EDGES;                    // NB*PBC (8.0 MB)
    int*            cnt   = (int*)(recs2 + (size_t)NB * PBC);   // 391*782
    int*            offs  = cnt + BIN_BLOCKS * NB;              // 391*782
    int*            tot   = offs + BIN_BLOCKS * NB;             // NB
    int*            base  = tot + NB;                           // NB+1

    k_cnt<<<dim3(BIN_BLOCKS), dim3(512), 0, stream>>>(ei, cnt);

    k_mscan<<<dim3((NB + 3) / 4), dim3(256), 0, stream>>>(cnt, offs, tot);

    k_scan<<<dim3(1), dim3(1024), 0, stream>>>(tot, base);

    k_bin2<<<dim3(BIN_BLOCKS), dim3(512), 0, stream>>>(ei, offs, base, recsr);

    k_sort<<<dim3(NB), dim3(256), 0, stream>>>(base, recsr, recs2);

    k_node1<<<dim3((N_NODES + 256) / 256), dim3(256), 0, stream>>>(
        x, w1_rel, w1_root, b1, xrh, agg);

    k_acc<<<dim3(ACC_BLOCKS), dim3(256), 0, stream>>>(recs2, tot, xrh, agg);

    k_node2<<<dim3((N_NODES + 256) / 256), dim3(256), 0, stream>>>(agg, xrh);

    k_acc<<<dim3(ACC_BLOCKS), dim3(256), 0, stream>>>(recs2, tot, xrh, agg);

    k_out<<<dim3((N_NODES + 255) / 256), dim3(256), 0, stream>>>(
        xrh, agg, w2_rel, w2_root, b2, out);
}

// Round 10
// 179.658 us; speedup vs baseline: 1.8442x; 1.2158x over previous
//
#include <hip/hip_runtime.h>

#define N_NODES 100000
#define N_EDGES 1600000
#define D_IN 32
#define D_HID 16
#define D_OUT 2

// dst bucketing: 128 nodes per bucket.
#define NPB 128
#define NB 782                       // ceil(100000/128)
#define NROWS (NB * NPB)             // 100096 padded feature rows
#define CHUNK 4096
#define PBLOCKS ((N_EDGES + CHUNK - 1) / CHUNK)   // 391
#define MSCAN_CHUNKS ((PBLOCKS + 63) / 64)        // 7

// Padded per-bucket record windows (mean fill 2046, 11 sigma headroom).
#define PBC 2560
#define SORT_CAP 2816
#define DUMMY_SRC 100000u            // zeroed feature row
#define DUMMY_REC ((127u << 17) | DUMMY_SRC)

// k_acc: 16 lanes/record, ACC_K records per group, 16 groups per block.
#define ACC_K 16
#define ACC_BPB (PBC / (16 * ACC_K)) // 10 blocks per bucket
#define ACC_BLOCKS (NB * ACC_BPB)    // 7820

__device__ __forceinline__ unsigned bfr(float x) {   // f32 -> bf16 (RNE)
    unsigned u = __float_as_uint(x);
    return (u + 0x7FFFu + ((u >> 16) & 1u)) >> 16;
}
__device__ __forceinline__ float bfu(unsigned lo16) {
    return __uint_as_float(lo16 << 16);
}

// ---------------------------------------------------------------------------
// Fused: per-block bucket histogram of dst  +  node-1 dense transform.
// The two are data-independent; the latency-bound histogram overlaps the
// VALU-bound transform within the same waves.
//   xr[i] (bf16) = x[i] @ w1_rel^T ;  agg[i] (f32) = x[i] @ w1_root^T + b1
// ---------------------------------------------------------------------------
__global__ __launch_bounds__(512) void k_hist_node1(
    const int* __restrict__ ei, const float* __restrict__ x,
    const float* __restrict__ w_rel, const float* __restrict__ w_root,
    const float* __restrict__ bb,
    unsigned short* __restrict__ xr, float* __restrict__ agg,
    int* __restrict__ cnt)
{
    __shared__ int h[NB];
    __shared__ float s_rel[D_HID * D_IN];
    __shared__ float s_root[D_HID * D_IN];
    __shared__ float s_b[D_HID];
    int blk = blockIdx.x, tid = threadIdx.x;

    for (int i = tid; i < D_HID * D_IN; i += 512) {
        s_rel[i]  = w_rel[i];
        s_root[i] = w_root[i];
    }
    if (tid < D_HID) s_b[tid] = bb[tid];
    for (int i = tid; i < NB; i += 512) h[i] = 0;
    __syncthreads();

    int e0 = blk * CHUNK;
    int e1 = min(e0 + CHUNK, N_EDGES);
    for (int e = e0 + tid; e < e1; e += 512)
        atomicAdd(&h[ei[N_EDGES + e] >> 7], 1);

    int node = blk * 512 + tid;                    // 391*512 = 200192 > 100001
    if (node == N_NODES) {                         // dummy zero row
        uint4* xp = (uint4*)(xr + (size_t)node * D_HID);
        xp[0] = make_uint4(0, 0, 0, 0);
        xp[1] = make_uint4(0, 0, 0, 0);
    } else if (node < N_NODES) {
        float row[D_IN];
        const float4* xp = (const float4*)(x + (size_t)node * D_IN);
#pragma unroll
        for (int i = 0; i < D_IN / 4; i++) {
            float4 v = xp[i];
            row[4*i+0] = v.x; row[4*i+1] = v.y; row[4*i+2] = v.z; row[4*i+3] = v.w;
        }
        float oa[D_HID], orr[D_HID];
#pragma unroll
        for (int o = 0; o < D_HID; o++) {
            float a = 0.f, r = s_b[o];
#pragma unroll
            for (int k = 0; k < D_IN; k++) {
                a += row[k] * s_rel[o * D_IN + k];
                r += row[k] * s_root[o * D_IN + k];
            }
            oa[o] = a; orr[o] = r;
        }
        unsigned p[8];
#pragma unroll
        for (int i = 0; i < 8; i++)
            p[i] = bfr(oa[2*i]) | (bfr(oa[2*i+1]) << 16);
        uint4* xrp = (uint4*)(xr + (size_t)node * D_HID);
        xrp[0] = make_uint4(p[0], p[1], p[2], p[3]);
        xrp[1] = make_uint4(p[4], p[5], p[6], p[7]);
        float4* aggp = (float4*)(agg + (size_t)node * D_HID);
#pragma unroll
        for (int i = 0; i < D_HID / 4; i++)
            aggp[i] = make_float4(orr[4*i], orr[4*i+1], orr[4*i+2], orr[4*i+3]);
    }
    __syncthreads();
    for (int i = tid; i < NB; i += 512) cnt[blk * NB + i] = h[i];
}

// ---------------------------------------------------------------------------
// Per-bucket exclusive scan over blocks (1 wave/bucket) -> offs, capped tot.
// No global base[] needed: recs2 windows are bucket-padded.
// ---------------------------------------------------------------------------
__global__ __launch_bounds__(256) void k_mscan(
    const int* __restrict__ cnt, int* __restrict__ offs, int* __restrict__ tot)
{
    int w = blockIdx.x * 4 + (threadIdx.x >> 6);
    int lane = threadIdx.x & 63;
    if (w >= NB) return;
    int running = 0;
    for (int c = 0; c < MSCAN_CHUNKS; c++) {
        int b2 = c * 64 + lane;
        int v = (b2 < PBLOCKS) ? cnt[b2 * NB + w] : 0;
        int incl = v;
#pragma unroll
        for (int off = 1; off < 64; off <<= 1) {
            int t = __shfl_up(incl, off);
            if (lane >= off) incl += t;
        }
        if (b2 < PBLOCKS) offs[b2 * NB + w] = running + incl - v;
        running += __shfl(incl, 63);
    }
    if (lane == 0) tot[w] = min(running, PBC);
}

// ---------------------------------------------------------------------------
// Bin edges as packed 4 B records directly into the padded bucket windows.
// rec = (dst&127)<<17 | src. LDS cursors preloaded with exact offsets.
// ---------------------------------------------------------------------------
__global__ __launch_bounds__(512) void k_bin2(
    const int* __restrict__ ei, const int* __restrict__ offs,
    unsigned* __restrict__ recs2)
{
    __shared__ int cur[NB];
    int blk = blockIdx.x, tid = threadIdx.x;
    for (int i = tid; i < NB; i += 512)
        cur[i] = i * PBC + offs[blk * NB + i];
    __syncthreads();
    int e0 = blk * CHUNK;
    int e1 = min(e0 + CHUNK, N_EDGES);
    for (int e = e0 + tid; e < e1; e += 512) {
        int src = ei[e];
        int dst = ei[N_EDGES + e];
        int bkt = dst >> 7;
        int idx = atomicAdd(&cur[bkt], 1);
        if (idx < (bkt + 1) * PBC)                 // 11-sigma overflow guard
            recs2[idx] = ((unsigned)(dst & (NPB - 1)) << 17) | (unsigned)src;
    }
}

// ---------------------------------------------------------------------------
// Per-bucket in-place counting sort by (dst&127): stage the window in LDS
// (single coalesced read), sort, write back, pad tail to ACC_K multiple.
// ---------------------------------------------------------------------------
__global__ __launch_bounds__(256) void k_sort(
    const int* __restrict__ tot, unsigned* __restrict__ recs2)
{
    __shared__ unsigned stage[SORT_CAP];
    __shared__ int hist[NPB];
    __shared__ int sc[NPB];
    __shared__ int cur[NPB];
    int b = blockIdx.x, tid = threadIdx.x;
    int n = tot[b];
    unsigned* w = recs2 + (size_t)b * PBC;
    if (tid < NPB) hist[tid] = 0;
    for (int i = tid; i < n; i += 256) stage[i] = w[i];
    __syncthreads();
    for (int i = tid; i < n; i += 256)
        atomicAdd(&hist[stage[i] >> 17], 1);
    __syncthreads();
    if (tid < NPB) sc[tid] = hist[tid];
    __syncthreads();
#pragma unroll
    for (int off = 1; off < NPB; off <<= 1) {
        int t = (tid >= off && tid < NPB) ? sc[tid - off] : 0;
        __syncthreads();
        if (tid < NPB) sc[tid] += t;
        __syncthreads();
    }
    if (tid < NPB) cur[tid] = sc[tid] - hist[tid];
    __syncthreads();
    for (int i = tid; i < n; i += 256) {
        unsigned r = stage[i];
        int slot = atomicAdd(&cur[r >> 17], 1);
        w[slot] = r;
    }
    int npad = (n + ACC_K - 1) & ~(ACC_K - 1);
    for (int i = n + tid; i < npad; i += 256) w[i] = DUMMY_REC;
}

// ---------------------------------------------------------------------------
// Generic 16-dim accumulate over dst-sorted padded records, bf16 sources.
// 16 lanes/record, ACC_K=16 records/group (16 independent gathers in flight),
// run-combining -> ~195k atomic flushes per layer.
// ---------------------------------------------------------------------------
__global__ __launch_bounds__(256) void k_acc(
    const unsigned* __restrict__ recs2, const int* __restrict__ tot,
    const unsigned short* __restrict__ srcf, float* __restrict__ dstf)
{
    int bucket = blockIdx.x / ACC_BPB;
    int blk    = blockIdx.x % ACC_BPB;
    int g = threadIdx.x >> 4;
    int f = threadIdx.x & (D_HID - 1);
    int r0 = (blk * 16 + g) * ACC_K;
    int n = tot[bucket];
    if (r0 >= n) return;
    const unsigned* rp = recs2 + (size_t)bucket * PBC + r0;

    unsigned e[ACC_K];
#pragma unroll
    for (int k = 0; k < ACC_K; k++) e[k] = rp[k];
    float v[ACC_K];
#pragma unroll
    for (int k = 0; k < ACC_K; k++)
        v[k] = bfu(srcf[(e[k] & 0x1FFFF) * D_HID + f]);

    int dbase = bucket * NPB;
    unsigned cur = e[0] >> 17;
    float acc = v[0];
#pragma unroll
    for (int k = 1; k < ACC_K; k++) {
        unsigned dl = e[k] >> 17;
        if (dl == cur) {
            acc += v[k];
        } else {
            atomicAdd(&dstf[(dbase + cur) * D_HID + f], acc);
            cur = dl;
            acc = v[k];
        }
    }
    atomicAdd(&dstf[(dbase + cur) * D_HID + f], acc);
}

// ---------------------------------------------------------------------------
// h = relu(agg1) as bf16; re-zero agg1 (becomes the layer-2 accumulator).
// ---------------------------------------------------------------------------
__global__ __launch_bounds__(256) void k_node2(
    float* __restrict__ agg, unsigned short* __restrict__ h)
{
    int node = blockIdx.x * blockDim.x + threadIdx.x;
    if (node > N_NODES) return;
    uint4* hp = (uint4*)(h + (size_t)node * D_HID);
    if (node == N_NODES) {
        hp[0] = make_uint4(0, 0, 0, 0);
        hp[1] = make_uint4(0, 0, 0, 0);
        return;
    }
    float4* ap = (float4*)(agg + (size_t)node * D_HID);
    float hv[D_HID];
#pragma unroll
    for (int i = 0; i < D_HID / 4; i++) {
        float4 v = ap[i];
        hv[4*i+0] = fmaxf(v.x, 0.f); hv[4*i+1] = fmaxf(v.y, 0.f);
        hv[4*i+2] = fmaxf(v.z, 0.f); hv[4*i+3] = fmaxf(v.w, 0.f);
        ap[i] = make_float4(0.f, 0.f, 0.f, 0.f);
    }
    unsigned p[8];
#pragma unroll
    for (int i = 0; i < 8; i++)
        p[i] = bfr(hv[2*i]) | (bfr(hv[2*i+1]) << 16);
    hp[0] = make_uint4(p[0], p[1], p[2], p[3]);
    hp[1] = make_uint4(p[4], p[5], p[6], p[7]);
}

// ---------------------------------------------------------------------------
// Final epilogue: out = aggH @ w2_rel^T + h @ w2_root^T + b2  (h is bf16).
// ---------------------------------------------------------------------------
__global__ __launch_bounds__(256) void k_out(
    const unsigned short* __restrict__ h, const float* __restrict__ aggh,
    const float* __restrict__ w_rel, const float* __restrict__ w_root,
    const float* __restrict__ b, float* __restrict__ outv)
{
    __shared__ float s_rel[D_OUT * D_HID];
    __shared__ float s_root[D_OUT * D_HID];
    __shared__ float s_b[D_OUT];
    if (threadIdx.x < D_OUT * D_HID) {
        s_rel[threadIdx.x]  = w_rel[threadIdx.x];
        s_root[threadIdx.x] = w_root[threadIdx.x];
    }
    if (threadIdx.x < D_OUT) s_b[threadIdx.x] = b[threadIdx.x];
    __syncthreads();

    int node = blockIdx.x * blockDim.x + threadIdx.x;
    if (node >= N_NODES) return;

    const uint4* hp = (const uint4*)(h + (size_t)node * D_HID);
    uint4 h0 = hp[0], h1 = hp[1];
    unsigned pk[8] = {h0.x, h0.y, h0.z, h0.w, h1.x, h1.y, h1.z, h1.w};
    float hv[D_HID];
#pragma unroll
    for (int i = 0; i < 8; i++) {
        hv[2*i]   = bfu(pk[i] & 0xFFFFu);
        hv[2*i+1] = __uint_as_float(pk[i] & 0xFFFF0000u);
    }

    float av[D_HID];
    const float4* ap = (const float4*)(aggh + (size_t)node * D_HID);
#pragma unroll
    for (int i = 0; i < D_HID / 4; i++) {
        float4 c = ap[i];
        av[4*i+0] = c.x; av[4*i+1] = c.y; av[4*i+2] = c.z; av[4*i+3] = c.w;
    }

    float o[D_OUT];
#pragma unroll
    for (int oo = 0; oo < D_OUT; oo++) {
        float r = s_b[oo];
#pragma unroll
        for (int k = 0; k < D_HID; k++)
            r += av[k] * s_rel[oo * D_HID + k] + hv[k] * s_root[oo * D_HID + k];
        o[oo] = r;
    }
    ((float2*)(outv + (size_t)node * D_OUT))[0] = make_float2(o[0], o[1]);
}

extern "C" void kernel_launch(void* const* d_in, const int* in_sizes, int n_in,
                              void* d_out, int out_size, void* d_ws, size_t ws_size,
                              hipStream_t stream) {
    const float* x       = (const float*)d_in[0];
    const int*   ei      = (const int*)  d_in[1];
    const float* w1_rel  = (const float*)d_in[2];
    const float* w1_root = (const float*)d_in[3];
    const float* b1      = (const float*)d_in[4];
    const float* w2_rel  = (const float*)d_in[5];
    const float* w2_root = (const float*)d_in[6];
    const float* b2      = (const float*)d_in[7];
    float* out = (float*)d_out;

    // Workspace (~20.1 MB; everything rewritten each call):
    float*          agg   = (float*)d_ws;                                  // NROWS*16 f32 (6.4 MB)
    unsigned short* xrh   = (unsigned short*)(agg + (size_t)NROWS * D_HID);// NROWS*16 bf16 (3.2 MB)
    unsigned*       recs2 = (unsigned*)(xrh + (size_t)NROWS * D_HID);      // NB*PBC (8.0 MB)
    int*            cnt   = (int*)(recs2 + (size_t)NB * PBC);              // 391*782
    int*            offs  = cnt + PBLOCKS * NB;                            // 391*782
    int*            tot   = offs + PBLOCKS * NB;                           // NB

    k_hist_node1<<<dim3(PBLOCKS), dim3(512), 0, stream>>>(
        ei, x, w1_rel, w1_root, b1, xrh, agg, cnt);

    k_mscan<<<dim3((NB + 3) / 4), dim3(256), 0, stream>>>(cnt, offs, tot);

    k_bin2<<<dim3(PBLOCKS), dim3(512), 0, stream>>>(ei, offs, recs2);

    k_sort<<<dim3(NB), dim3(256), 0, stream>>>(tot, recs2);

    k_acc<<<dim3(ACC_BLOCKS), dim3(256), 0, stream>>>(recs2, tot, xrh, agg);

    k_node2<<<dim3((N_NODES + 256) / 256), dim3(256), 0, stream>>>(agg, xrh);

    k_acc<<<dim3(ACC_BLOCKS), dim3(256), 0, stream>>>(recs2, tot, xrh, agg);

    k_out<<<dim3((N_NODES + 255) / 256), dim3(256), 0, stream>>>(
        xrh, agg, w2_rel, w2_root, b2, out);
}

// Round 11
// 170.123 us; speedup vs baseline: 1.9476x; 1.0560x over previous
//
#include <hip/hip_runtime.h>

#define N_NODES 100000
#define N_EDGES 1600000
#define D_IN 32
#define D_HID 16
#define D_OUT 2

// dst bucketing: 128 nodes per bucket.
#define NPB 128
#define NB 782                       // ceil(100000/128)
#define NROWS (NB * NPB)             // 100096 padded feature rows
#define CHUNK 4096
#define PBLOCKS ((N_EDGES + CHUNK - 1) / CHUNK)   // 391
#define MSCAN_CHUNKS ((PBLOCKS + 63) / 64)        // 7

// Padded per-bucket record windows (mean fill 2046, 11 sigma headroom).
#define PBC 2560
#define SORT_CAP 2816
#define DUMMY_SRC 100000u            // zeroed feature row
#define DUMMY_REC ((127u << 17) | DUMMY_SRC)
#define PAD_ALIGN 32                 // window padded to multiple of 32 records

// Layer-1 acc: 16 lanes/record, ACC_K records per group, 16 groups/block.
#define ACC_K 32
#define ACC_BPB (PBC / (16 * ACC_K))   // 5 blocks per bucket
#define ACC_BLOCKS (NB * ACC_BPB)      // 3910

// Layer-2 acc: 2 lanes/record, ACC2_K records per group, 128 groups/block.
#define ACC2_K 16
#define ACC2_BPB 2                     // 2*128*16 = 4096 slots >= PBC
#define ACC2_BLOCKS (NB * ACC2_BPB)    // 1564

__device__ __forceinline__ unsigned bfr(float x) {   // f32 -> bf16 (RNE)
    unsigned u = __float_as_uint(x);
    return (u + 0x7FFFu + ((u >> 16) & 1u)) >> 16;
}
__device__ __forceinline__ float bfu(unsigned lo16) {
    return __uint_as_float(lo16 << 16);
}

// ---------------------------------------------------------------------------
// Fused: per-block bucket histogram of dst  +  node-1 dense transform.
//   xr[i] (bf16) = x[i] @ w1_rel^T ;  agg[i] (f32) = x[i] @ w1_root^T + b1
// ---------------------------------------------------------------------------
__global__ __launch_bounds__(512) void k_hist_node1(
    const int* __restrict__ ei, const float* __restrict__ x,
    const float* __restrict__ w_rel, const float* __restrict__ w_root,
    const float* __restrict__ bb,
    unsigned short* __restrict__ xr, float* __restrict__ agg,
    int* __restrict__ cnt)
{
    __shared__ int h[NB];
    __shared__ float s_rel[D_HID * D_IN];
    __shared__ float s_root[D_HID * D_IN];
    __shared__ float s_b[D_HID];
    int blk = blockIdx.x, tid = threadIdx.x;

    for (int i = tid; i < D_HID * D_IN; i += 512) {
        s_rel[i]  = w_rel[i];
        s_root[i] = w_root[i];
    }
    if (tid < D_HID) s_b[tid] = bb[tid];
    for (int i = tid; i < NB; i += 512) h[i] = 0;
    __syncthreads();

    int e0 = blk * CHUNK;
    int e1 = min(e0 + CHUNK, N_EDGES);
    for (int e = e0 + tid; e < e1; e += 512)
        atomicAdd(&h[ei[N_EDGES + e] >> 7], 1);

    int node = blk * 512 + tid;                    // 391*512 = 200192 > 100001
    if (node == N_NODES) {                         // dummy zero row
        uint4* xp = (uint4*)(xr + (size_t)node * D_HID);
        xp[0] = make_uint4(0, 0, 0, 0);
        xp[1] = make_uint4(0, 0, 0, 0);
    } else if (node < N_NODES) {
        float row[D_IN];
        const float4* xp = (const float4*)(x + (size_t)node * D_IN);
#pragma unroll
        for (int i = 0; i < D_IN / 4; i++) {
            float4 v = xp[i];
            row[4*i+0] = v.x; row[4*i+1] = v.y; row[4*i+2] = v.z; row[4*i+3] = v.w;
        }
        float oa[D_HID], orr[D_HID];
#pragma unroll
        for (int o = 0; o < D_HID; o++) {
            float a = 0.f, r = s_b[o];
#pragma unroll
            for (int k = 0; k < D_IN; k++) {
                a += row[k] * s_rel[o * D_IN + k];
                r += row[k] * s_root[o * D_IN + k];
            }
            oa[o] = a; orr[o] = r;
        }
        unsigned p[8];
#pragma unroll
        for (int i = 0; i < 8; i++)
            p[i] = bfr(oa[2*i]) | (bfr(oa[2*i+1]) << 16);
        uint4* xrp = (uint4*)(xr + (size_t)node * D_HID);
        xrp[0] = make_uint4(p[0], p[1], p[2], p[3]);
        xrp[1] = make_uint4(p[4], p[5], p[6], p[7]);
        float4* aggp = (float4*)(agg + (size_t)node * D_HID);
#pragma unroll
        for (int i = 0; i < D_HID / 4; i++)
            aggp[i] = make_float4(orr[4*i], orr[4*i+1], orr[4*i+2], orr[4*i+3]);
    }
    __syncthreads();
    for (int i = tid; i < NB; i += 512) cnt[blk * NB + i] = h[i];
}

// ---------------------------------------------------------------------------
// Per-bucket exclusive scan over blocks (1 wave/bucket) -> offs, capped tot.
// ---------------------------------------------------------------------------
__global__ __launch_bounds__(256) void k_mscan(
    const int* __restrict__ cnt, int* __restrict__ offs, int* __restrict__ tot)
{
    int w = blockIdx.x * 4 + (threadIdx.x >> 6);
    int lane = threadIdx.x & 63;
    if (w >= NB) return;
    int running = 0;
    for (int c = 0; c < MSCAN_CHUNKS; c++) {
        int b2 = c * 64 + lane;
        int v = (b2 < PBLOCKS) ? cnt[b2 * NB + w] : 0;
        int incl = v;
#pragma unroll
        for (int off = 1; off < 64; off <<= 1) {
            int t = __shfl_up(incl, off);
            if (lane >= off) incl += t;
        }
        if (b2 < PBLOCKS) offs[b2 * NB + w] = running + incl - v;
        running += __shfl(incl, 63);
    }
    if (lane == 0) tot[w] = min(running, PBC);
}

// ---------------------------------------------------------------------------
// Bin edges as packed 4 B records directly into the padded bucket windows.
// rec = (dst&127)<<17 | src.
// ---------------------------------------------------------------------------
__global__ __launch_bounds__(512) void k_bin2(
    const int* __restrict__ ei, const int* __restrict__ offs,
    unsigned* __restrict__ recs2)
{
    __shared__ int cur[NB];
    int blk = blockIdx.x, tid = threadIdx.x;
    for (int i = tid; i < NB; i += 512)
        cur[i] = i * PBC + offs[blk * NB + i];
    __syncthreads();
    int e0 = blk * CHUNK;
    int e1 = min(e0 + CHUNK, N_EDGES);
    for (int e = e0 + tid; e < e1; e += 512) {
        int src = ei[e];
        int dst = ei[N_EDGES + e];
        int bkt = dst >> 7;
        int idx = atomicAdd(&cur[bkt], 1);
        if (idx < (bkt + 1) * PBC)                 // 11-sigma overflow guard
            recs2[idx] = ((unsigned)(dst & (NPB - 1)) << 17) | (unsigned)src;
    }
}

// ---------------------------------------------------------------------------
// Per-bucket in-place counting sort by (dst&127); pad tail to PAD_ALIGN.
// ---------------------------------------------------------------------------
__global__ __launch_bounds__(256) void k_sort(
    const int* __restrict__ tot, unsigned* __restrict__ recs2)
{
    __shared__ unsigned stage[SORT_CAP];
    __shared__ int hist[NPB];
    __shared__ int sc[NPB];
    __shared__ int cur[NPB];
    int b = blockIdx.x, tid = threadIdx.x;
    int n = tot[b];
    unsigned* w = recs2 + (size_t)b * PBC;
    if (tid < NPB) hist[tid] = 0;
    for (int i = tid; i < n; i += 256) stage[i] = w[i];
    __syncthreads();
    for (int i = tid; i < n; i += 256)
        atomicAdd(&hist[stage[i] >> 17], 1);
    __syncthreads();
    if (tid < NPB) sc[tid] = hist[tid];
    __syncthreads();
#pragma unroll
    for (int off = 1; off < NPB; off <<= 1) {
        int t = (tid >= off && tid < NPB) ? sc[tid - off] : 0;
        __syncthreads();
        if (tid < NPB) sc[tid] += t;
        __syncthreads();
    }
    if (tid < NPB) cur[tid] = sc[tid] - hist[tid];
    __syncthreads();
    for (int i = tid; i < n; i += 256) {
        unsigned r = stage[i];
        int slot = atomicAdd(&cur[r >> 17], 1);
        w[slot] = r;
    }
    int npad = (n + PAD_ALIGN - 1) & ~(PAD_ALIGN - 1);
    for (int i = n + tid; i < npad; i += 256) w[i] = DUMMY_REC;
}

// ---------------------------------------------------------------------------
// Layer-1 accumulate: 16 lanes/record, ACC_K=32 records/group, bf16 sources,
// run-combining -> ~150k 64 B atomic flushes.
// ---------------------------------------------------------------------------
__global__ __launch_bounds__(256) void k_acc(
    const unsigned* __restrict__ recs2, const int* __restrict__ tot,
    const unsigned short* __restrict__ srcf, float* __restrict__ dstf)
{
    int bucket = blockIdx.x / ACC_BPB;
    int blk    = blockIdx.x % ACC_BPB;
    int g = threadIdx.x >> 4;
    int f = threadIdx.x & (D_HID - 1);
    int r0 = (blk * 16 + g) * ACC_K;
    int n = tot[bucket];
    if (r0 >= n) return;
    const unsigned* rp = recs2 + (size_t)bucket * PBC + r0;

    unsigned e[ACC_K];
#pragma unroll
    for (int k = 0; k < ACC_K; k++) e[k] = rp[k];
    float v[ACC_K];
#pragma unroll
    for (int k = 0; k < ACC_K; k++)
        v[k] = bfu(srcf[(e[k] & 0x1FFFF) * D_HID + f]);

    int dbase = bucket * NPB;
    unsigned cur = e[0] >> 17;
    float acc = v[0];
#pragma unroll
    for (int k = 1; k < ACC_K; k++) {
        unsigned dl = e[k] >> 17;
        if (dl == cur) {
            acc += v[k];
        } else {
            atomicAdd(&dstf[(dbase + cur) * D_HID + f], acc);
            cur = dl;
            acc = v[k];
        }
    }
    atomicAdd(&dstf[(dbase + cur) * D_HID + f], acc);
}

// ---------------------------------------------------------------------------
// Fold layer-2 weights per node:  h = relu(agg1);
//   hr[i]  = h @ w2_rel^T   (float2; gathered by k_acc2)
//   out[i] = h @ w2_root^T + b2   (accumulator init, written directly)
// node == N_NODES zeroes the dummy hr row.
// ---------------------------------------------------------------------------
__global__ __launch_bounds__(256) void k_node2h(
    const float* __restrict__ agg,
    const float* __restrict__ w_rel, const float* __restrict__ w_root,
    const float* __restrict__ b,
    float* __restrict__ hr, float* __restrict__ outv)
{
    __shared__ float s_rel[D_OUT * D_HID];
    __shared__ float s_root[D_OUT * D_HID];
    __shared__ float s_b[D_OUT];
    if (threadIdx.x < D_OUT * D_HID) {
        s_rel[threadIdx.x]  = w_rel[threadIdx.x];
        s_root[threadIdx.x] = w_root[threadIdx.x];
    }
    if (threadIdx.x < D_OUT) s_b[threadIdx.x] = b[threadIdx.x];
    __syncthreads();

    int node = blockIdx.x * blockDim.x + threadIdx.x;
    if (node > N_NODES) return;
    if (node == N_NODES) {
        ((float2*)hr)[node] = make_float2(0.f, 0.f);
        return;
    }

    float hv[D_HID];
    const float4* ap = (const float4*)(agg + (size_t)node * D_HID);
#pragma unroll
    for (int i = 0; i < D_HID / 4; i++) {
        float4 v = ap[i];
        hv[4*i+0] = fmaxf(v.x, 0.f); hv[4*i+1] = fmaxf(v.y, 0.f);
        hv[4*i+2] = fmaxf(v.z, 0.f); hv[4*i+3] = fmaxf(v.w, 0.f);
    }

    float o_rel[D_OUT], o_root[D_OUT];
#pragma unroll
    for (int o = 0; o < D_OUT; o++) {
        float a = 0.f, r = s_b[o];
#pragma unroll
        for (int k = 0; k < D_HID; k++) {
            a += hv[k] * s_rel[o * D_HID + k];
            r += hv[k] * s_root[o * D_HID + k];
        }
        o_rel[o] = a; o_root[o] = r;
    }
    ((float2*)hr)[node]   = make_float2(o_rel[0], o_rel[1]);
    ((float2*)outv)[node] = make_float2(o_root[0], o_root[1]);
}

// ---------------------------------------------------------------------------
// Layer-2 accumulate: 2 lanes/record, ACC2_K=16 records/group, float2 hr
// gathers (0.8 MB, L2-resident), run-combining, flushes straight into out.
// Dummy recs in the last bucket map to rows >= N_NODES -> bounds-guarded.
// ---------------------------------------------------------------------------
__global__ __launch_bounds__(256) void k_acc2(
    const unsigned* __restrict__ recs2, const int* __restrict__ tot,
    const float* __restrict__ hr, float* __restrict__ outv)
{
    int bucket = blockIdx.x / ACC2_BPB;
    int blk    = blockIdx.x % ACC2_BPB;
    int g = threadIdx.x >> 1;
    int f = threadIdx.x & 1;
    int r0 = (blk * 128 + g) * ACC2_K;
    int n = tot[bucket];
    if (r0 >= n) return;
    const unsigned* rp = recs2 + (size_t)bucket * PBC + r0;

    unsigned e[ACC2_K];
#pragma unroll
    for (int k = 0; k < ACC2_K; k++) e[k] = rp[k];
    float v[ACC2_K];
#pragma unroll
    for (int k = 0; k < ACC2_K; k++)
        v[k] = hr[(e[k] & 0x1FFFF) * D_OUT + f];

    int dbase = bucket * NPB;
    unsigned cur = e[0] >> 17;
    float acc = v[0];
#pragma unroll
    for (int k = 1; k < ACC2_K; k++) {
        unsigned dl = e[k] >> 17;
        if (dl == cur) {
            acc += v[k];
        } else {
            int d = dbase + (int)cur;
            if (d < N_NODES) atomicAdd(&outv[d * D_OUT + f], acc);
            cur = dl;
            acc = v[k];
        }
    }
    int d = dbase + (int)cur;
    if (d < N_NODES) atomicAdd(&outv[d * D_OUT + f], acc);
}

extern "C" void kernel_launch(void* const* d_in, const int* in_sizes, int n_in,
                              void* d_out, int out_size, void* d_ws, size_t ws_size,
                              hipStream_t stream) {
    const float* x       = (const float*)d_in[0];
    const int*   ei      = (const int*)  d_in[1];
    const float* w1_rel  = (const float*)d_in[2];
    const float* w1_root = (const float*)d_in[3];
    const float* b1      = (const float*)d_in[4];
    const float* w2_rel  = (const float*)d_in[5];
    const float* w2_root = (const float*)d_in[6];
    const float* b2      = (const float*)d_in[7];
    float* out = (float*)d_out;

    // Workspace (~21 MB; everything rewritten each call):
    float*          agg   = (float*)d_ws;                                  // NROWS*16 f32 (6.4 MB)
    unsigned short* xrh   = (unsigned short*)(agg + (size_t)NROWS * D_HID);// NROWS*16 bf16 (3.2 MB)
    unsigned*       recs2 = (unsigned*)(xrh + (size_t)NROWS * D_HID);      // NB*PBC (8.0 MB)
    float*          hr    = (float*)(recs2 + (size_t)NB * PBC);            // NROWS*2 f32 (0.8 MB)
    int*            cnt   = (int*)(hr + (size_t)NROWS * D_OUT);            // 391*782
    int*            offs  = cnt + PBLOCKS * NB;                            // 391*782
    int*            tot   = offs + PBLOCKS * NB;                           // NB

    k_hist_node1<<<dim3(PBLOCKS), dim3(512), 0, stream>>>(
        ei, x, w1_rel, w1_root, b1, xrh, agg, cnt);

    k_mscan<<<dim3((NB + 3) / 4), dim3(256), 0, stream>>>(cnt, offs, tot);

    k_bin2<<<dim3(PBLOCKS), dim3(512), 0, stream>>>(ei, offs, recs2);

    k_sort<<<dim3(NB), dim3(256), 0, stream>>>(tot, recs2);

    k_acc<<<dim3(ACC_BLOCKS), dim3(256), 0, stream>>>(recs2, tot, xrh, agg);

    k_node2h<<<dim3((N_NODES + 256) / 256), dim3(256), 0, stream>>>(
        agg, w2_rel, w2_root, b2, hr, out);

    k_acc2<<<dim3(ACC2_BLOCKS), dim3(256), 0, stream>>>(recs2, tot, hr, out);
}

// Round 12
// 169.146 us; speedup vs baseline: 1.9588x; 1.0058x over previous
//
#include <hip/hip_runtime.h>

#define N_NODES 100000
#define N_EDGES 1600000
#define D_IN 32
#define D_HID 16
#define D_OUT 2

// dst bucketing: 128 nodes per bucket.
#define NPB 128
#define NB 782                       // ceil(100000/128)
#define NROWS (NB * NPB)             // 100096 padded feature rows
#define CHUNK 4096
#define PBLOCKS ((N_EDGES + CHUNK - 1) / CHUNK)   // 391
#define MSCAN_CHUNKS ((PBLOCKS + 63) / 64)        // 7

// Padded per-bucket record windows (mean fill 2046, 11 sigma headroom).
#define PBC 2560
#define DUMMY_SRC 100000u            // zeroed feature row
#define DUMMY_REC ((127u << 17) | DUMMY_SRC)
#define PAD_ALIGN 16

// Layer-2 acc: 2 lanes/record, ACC2_K records per group, 128 groups/block.
#define ACC2_K 16
#define ACC2_BPB 2                     // 2*128*16 = 4096 slots >= PBC
#define ACC2_BLOCKS (NB * ACC2_BPB)    // 1564

__device__ __forceinline__ unsigned bfr(float x) {   // f32 -> bf16 (RNE)
    unsigned u = __float_as_uint(x);
    return (u + 0x7FFFu + ((u >> 16) & 1u)) >> 16;
}
__device__ __forceinline__ float bfu(unsigned lo16) {
    return __uint_as_float(lo16 << 16);
}

// ---------------------------------------------------------------------------
// Fused: per-block bucket histogram of dst  +  node-1 dense transform.
//   xr[i] (bf16) = x[i] @ w1_rel^T ;  agg[i] (f32) = x[i] @ w1_root^T + b1
// ---------------------------------------------------------------------------
__global__ __launch_bounds__(512) void k_hist_node1(
    const int* __restrict__ ei, const float* __restrict__ x,
    const float* __restrict__ w_rel, const float* __restrict__ w_root,
    const float* __restrict__ bb,
    unsigned short* __restrict__ xr, float* __restrict__ agg,
    int* __restrict__ cnt)
{
    __shared__ int h[NB];
    __shared__ float s_rel[D_HID * D_IN];
    __shared__ float s_root[D_HID * D_IN];
    __shared__ float s_b[D_HID];
    int blk = blockIdx.x, tid = threadIdx.x;

    for (int i = tid; i < D_HID * D_IN; i += 512) {
        s_rel[i]  = w_rel[i];
        s_root[i] = w_root[i];
    }
    if (tid < D_HID) s_b[tid] = bb[tid];
    for (int i = tid; i < NB; i += 512) h[i] = 0;
    __syncthreads();

    int e0 = blk * CHUNK;
    int e1 = min(e0 + CHUNK, N_EDGES);
    for (int e = e0 + tid; e < e1; e += 512)
        atomicAdd(&h[ei[N_EDGES + e] >> 7], 1);

    int node = blk * 512 + tid;                    // 391*512 = 200192 > 100001
    if (node == N_NODES) {                         // dummy zero row
        uint4* xp = (uint4*)(xr + (size_t)node * D_HID);
        xp[0] = make_uint4(0, 0, 0, 0);
        xp[1] = make_uint4(0, 0, 0, 0);
    } else if (node < N_NODES) {
        float row[D_IN];
        const float4* xp = (const float4*)(x + (size_t)node * D_IN);
#pragma unroll
        for (int i = 0; i < D_IN / 4; i++) {
            float4 v = xp[i];
            row[4*i+0] = v.x; row[4*i+1] = v.y; row[4*i+2] = v.z; row[4*i+3] = v.w;
        }
        float oa[D_HID], orr[D_HID];
#pragma unroll
        for (int o = 0; o < D_HID; o++) {
            float a = 0.f, r = s_b[o];
#pragma unroll
            for (int k = 0; k < D_IN; k++) {
                a += row[k] * s_rel[o * D_IN + k];
                r += row[k] * s_root[o * D_IN + k];
            }
            oa[o] = a; orr[o] = r;
        }
        unsigned p[8];
#pragma unroll
        for (int i = 0; i < 8; i++)
            p[i] = bfr(oa[2*i]) | (bfr(oa[2*i+1]) << 16);
        uint4* xrp = (uint4*)(xr + (size_t)node * D_HID);
        xrp[0] = make_uint4(p[0], p[1], p[2], p[3]);
        xrp[1] = make_uint4(p[4], p[5], p[6], p[7]);
        float4* aggp = (float4*)(agg + (size_t)node * D_HID);
#pragma unroll
        for (int i = 0; i < D_HID / 4; i++)
            aggp[i] = make_float4(orr[4*i], orr[4*i+1], orr[4*i+2], orr[4*i+3]);
    }
    __syncthreads();
    for (int i = tid; i < NB; i += 512) cnt[blk * NB + i] = h[i];
}

// ---------------------------------------------------------------------------
// Per-bucket exclusive scan over blocks (1 wave/bucket) -> offs, capped tot.
// ---------------------------------------------------------------------------
__global__ __launch_bounds__(256) void k_mscan(
    const int* __restrict__ cnt, int* __restrict__ offs, int* __restrict__ tot)
{
    int w = blockIdx.x * 4 + (threadIdx.x >> 6);
    int lane = threadIdx.x & 63;
    if (w >= NB) return;
    int running = 0;
    for (int c = 0; c < MSCAN_CHUNKS; c++) {
        int b2 = c * 64 + lane;
        int v = (b2 < PBLOCKS) ? cnt[b2 * NB + w] : 0;
        int incl = v;
#pragma unroll
        for (int off = 1; off < 64; off <<= 1) {
            int t = __shfl_up(incl, off);
            if (lane >= off) incl += t;
        }
        if (b2 < PBLOCKS) offs[b2 * NB + w] = running + incl - v;
        running += __shfl(incl, 63);
    }
    if (lane == 0) tot[w] = min(running, PBC);
}

// ---------------------------------------------------------------------------
// Bin edges as packed 4 B records directly into the padded bucket windows.
// rec = (dst&127)<<17 | src.
// ---------------------------------------------------------------------------
__global__ __launch_bounds__(512) void k_bin2(
    const int* __restrict__ ei, const int* __restrict__ offs,
    unsigned* __restrict__ recs2)
{
    __shared__ int cur[NB];
    int blk = blockIdx.x, tid = threadIdx.x;
    for (int i = tid; i < NB; i += 512)
        cur[i] = i * PBC + offs[blk * NB + i];
    __syncthreads();
    int e0 = blk * CHUNK;
    int e1 = min(e0 + CHUNK, N_EDGES);
    for (int e = e0 + tid; e < e1; e += 512) {
        int src = ei[e];
        int dst = ei[N_EDGES + e];
        int bkt = dst >> 7;
        int idx = atomicAdd(&cur[bkt], 1);
        if (idx < (bkt + 1) * PBC)                 // 11-sigma overflow guard
            recs2[idx] = ((unsigned)(dst & (NPB - 1)) << 17) | (unsigned)src;
    }
}

// ---------------------------------------------------------------------------
// Fused per-bucket sort + layer-1 accumulate (one 512-thread block/bucket):
//  1. stage the bucket window in LDS (coalesced read)
//  2. counting-sort by (dst&127) into a second LDS array, pad to 16
//  3. write sorted records back coalesced (consumed later by k_acc2)
//  4. accumulate: 32 groups x 16 lanes, 16-record register chunks from LDS,
//     16 independent bf16 line-gathers in flight, run-combining, atomic
//     flush into agg (~200 flushes/bucket). No LDS atomics in gather loop.
// ---------------------------------------------------------------------------
__global__ __launch_bounds__(512) void k_sortacc(
    const int* __restrict__ tot, unsigned* __restrict__ recs2,
    const unsigned short* __restrict__ srcf, float* __restrict__ dstf)
{
    __shared__ unsigned stage[PBC];
    __shared__ unsigned sorted[PBC];
    __shared__ int hist[NPB], sc[NPB], cur[NPB];
    int b = blockIdx.x, tid = threadIdx.x;
    int n = tot[b];
    unsigned* w = recs2 + (size_t)b * PBC;

    if (tid < NPB) hist[tid] = 0;
    for (int i = tid; i < n; i += 512) stage[i] = w[i];
    __syncthreads();
    for (int i = tid; i < n; i += 512)
        atomicAdd(&hist[stage[i] >> 17], 1);
    __syncthreads();
    if (tid < NPB) sc[tid] = hist[tid];
    __syncthreads();
#pragma unroll
    for (int off = 1; off < NPB; off <<= 1) {
        int t = (tid >= off && tid < NPB) ? sc[tid - off] : 0;
        __syncthreads();
        if (tid < NPB) sc[tid] += t;
        __syncthreads();
    }
    if (tid < NPB) cur[tid] = sc[tid] - hist[tid];
    __syncthreads();
    for (int i = tid; i < n; i += 512) {
        unsigned r = stage[i];
        int slot = atomicAdd(&cur[r >> 17], 1);
        sorted[slot] = r;
    }
    int npad = (n + PAD_ALIGN - 1) & ~(PAD_ALIGN - 1);
    for (int i = n + tid; i < npad; i += 512) sorted[i] = DUMMY_REC;
    __syncthreads();

    // write back sorted (sequential, coalesced) for k_acc2
    for (int i = tid; i < npad; i += 512) w[i] = sorted[i];

    // layer-1 accumulate straight from LDS
    int g = tid >> 4;                 // 0..31
    int f = tid & (D_HID - 1);
    int dbase = b * NPB;
    for (int base = g * 16; base < npad; base += 32 * 16) {
        unsigned e[16];
#pragma unroll
        for (int k = 0; k < 16; k++) e[k] = sorted[base + k];
        float v[16];
#pragma unroll
        for (int k = 0; k < 16; k++)
            v[k] = bfu(srcf[(e[k] & 0x1FFFF) * D_HID + f]);

        unsigned curd = e[0] >> 17;
        float acc = v[0];
#pragma unroll
        for (int k = 1; k < 16; k++) {
            unsigned dl = e[k] >> 17;
            if (dl == curd) {
                acc += v[k];
            } else {
                atomicAdd(&dstf[(dbase + curd) * D_HID + f], acc);
                curd = dl;
                acc = v[k];
            }
        }
        atomicAdd(&dstf[(dbase + curd) * D_HID + f], acc);
    }
}

// ---------------------------------------------------------------------------
// Fold layer-2 weights per node:  h = relu(agg1);
//   hr[i]  = h @ w2_rel^T   (float2; gathered by k_acc2)
//   out[i] = h @ w2_root^T + b2   (accumulator init, written directly)
// ---------------------------------------------------------------------------
__global__ __launch_bounds__(256) void k_node2h(
    const float* __restrict__ agg,
    const float* __restrict__ w_rel, const float* __restrict__ w_root,
    const float* __restrict__ b,
    float* __restrict__ hr, float* __restrict__ outv)
{
    __shared__ float s_rel[D_OUT * D_HID];
    __shared__ float s_root[D_OUT * D_HID];
    __shared__ float s_b[D_OUT];
    if (threadIdx.x < D_OUT * D_HID) {
        s_rel[threadIdx.x]  = w_rel[threadIdx.x];
        s_root[threadIdx.x] = w_root[threadIdx.x];
    }
    if (threadIdx.x < D_OUT) s_b[threadIdx.x] = b[threadIdx.x];
    __syncthreads();

    int node = blockIdx.x * blockDim.x + threadIdx.x;
    if (node > N_NODES) return;
    if (node == N_NODES) {
        ((float2*)hr)[node] = make_float2(0.f, 0.f);
        return;
    }

    float hv[D_HID];
    const float4* ap = (const float4*)(agg + (size_t)node * D_HID);
#pragma unroll
    for (int i = 0; i < D_HID / 4; i++) {
        float4 v = ap[i];
        hv[4*i+0] = fmaxf(v.x, 0.f); hv[4*i+1] = fmaxf(v.y, 0.f);
        hv[4*i+2] = fmaxf(v.z, 0.f); hv[4*i+3] = fmaxf(v.w, 0.f);
    }

    float o_rel[D_OUT], o_root[D_OUT];
#pragma unroll
    for (int o = 0; o < D_OUT; o++) {
        float a = 0.f, r = s_b[o];
#pragma unroll
        for (int k = 0; k < D_HID; k++) {
            a += hv[k] * s_rel[o * D_HID + k];
            r += hv[k] * s_root[o * D_HID + k];
        }
        o_rel[o] = a; o_root[o] = r;
    }
    ((float2*)hr)[node]   = make_float2(o_rel[0], o_rel[1]);
    ((float2*)outv)[node] = make_float2(o_root[0], o_root[1]);
}

// ---------------------------------------------------------------------------
// Layer-2 accumulate: 2 lanes/record, ACC2_K=16 records/group, float2 hr
// gathers (0.8 MB, L2-resident), run-combining, flushes straight into out.
// Dummy/tail recs map to row >= N_NODES in last bucket -> bounds-guarded;
// elsewhere they contribute hr[DUMMY_SRC] = 0.
// ---------------------------------------------------------------------------
__global__ __launch_bounds__(256) void k_acc2(
    const unsigned* __restrict__ recs2, const int* __restrict__ tot,
    const float* __restrict__ hr, float* __restrict__ outv)
{
    int bucket = blockIdx.x / ACC2_BPB;
    int blk    = blockIdx.x % ACC2_BPB;
    int g = threadIdx.x >> 1;
    int f = threadIdx.x & 1;
    int r0 = (blk * 128 + g) * ACC2_K;
    int n = tot[bucket];
    if (r0 >= n) return;
    const unsigned* rp = recs2 + (size_t)bucket * PBC + r0;

    unsigned e[ACC2_K];
#pragma unroll
    for (int k = 0; k < ACC2_K; k++) e[k] = rp[k];
    float v[ACC2_K];
#pragma unroll
    for (int k = 0; k < ACC2_K; k++)
        v[k] = hr[(e[k] & 0x1FFFF) * D_OUT + f];

    int dbase = bucket * NPB;
    unsigned cur = e[0] >> 17;
    float acc = v[0];
#pragma unroll
    for (int k = 1; k < ACC2_K; k++) {
        unsigned dl = e[k] >> 17;
        if (dl == cur) {
            acc += v[k];
        } else {
            int d = dbase + (int)cur;
            if (d < N_NODES) atomicAdd(&outv[d * D_OUT + f], acc);
            cur = dl;
            acc = v[k];
        }
    }
    int d = dbase + (int)cur;
    if (d < N_NODES) atomicAdd(&outv[d * D_OUT + f], acc);
}

extern "C" void kernel_launch(void* const* d_in, const int* in_sizes, int n_in,
                              void* d_out, int out_size, void* d_ws, size_t ws_size,
                              hipStream_t stream) {
    const float* x       = (const float*)d_in[0];
    const int*   ei      = (const int*)  d_in[1];
    const float* w1_rel  = (const float*)d_in[2];
    const float* w1_root = (const float*)d_in[3];
    const float* b1      = (const float*)d_in[4];
    const float* w2_rel  = (const float*)d_in[5];
    const float* w2_root = (const float*)d_in[6];
    const float* b2      = (const float*)d_in[7];
    float* out = (float*)d_out;

    // Workspace (~21 MB; everything rewritten each call):
    float*          agg   = (float*)d_ws;                                  // NROWS*16 f32 (6.4 MB)
    unsigned short* xrh   = (unsigned short*)(agg + (size_t)NROWS * D_HID);// NROWS*16 bf16 (3.2 MB)
    unsigned*       recs2 = (unsigned*)(xrh + (size_t)NROWS * D_HID);      // NB*PBC (8.0 MB)
    float*          hr    = (float*)(recs2 + (size_t)NB * PBC);            // NROWS*2 f32 (0.8 MB)
    int*            cnt   = (int*)(hr + (size_t)NROWS * D_OUT);            // 391*782
    int*            offs  = cnt + PBLOCKS * NB;                            // 391*782
    int*            tot   = offs + PBLOCKS * NB;                           // NB

    k_hist_node1<<<dim3(PBLOCKS), dim3(512), 0, stream>>>(
        ei, x, w1_rel, w1_root, b1, xrh, agg, cnt);

    k_mscan<<<dim3((NB + 3) / 4), dim3(256), 0, stream>>>(cnt, offs, tot);

    k_bin2<<<dim3(PBLOCKS), dim3(512), 0, stream>>>(ei, offs, recs2);

    k_sortacc<<<dim3(NB), dim3(512), 0, stream>>>(tot, recs2, xrh, agg);

    k_node2h<<<dim3((N_NODES + 256) / 256), dim3(256), 0, stream>>>(
        agg, w2_rel, w2_root, b2, hr, out);

    k_acc2<<<dim3(ACC2_BLOCKS), dim3(256), 0, stream>>>(recs2, tot, hr, out);
}